// Round 1
// baseline (3779.195 us; speedup 1.0000x reference)
//
#include <hip/hip_runtime.h>
#include <math.h>

#define BB 4
#define CC 512
#define TT 2048
#define HH 8
#define DD 64
#define WLOC 16

static constexpr float SCALE = 0.125f;   // D^-0.5, D=64

// ======================= RoPE cos/sin table =======================
// ctab/stab[t*32+i] = cos/sin(t * 10000^(-2i/64)); accurate libm trig once,
// consumed by the GEMM epilogue (avoids per-element trig, G13/AppB idiom).
__global__ void rope_table_kernel(float* __restrict__ ctab, float* __restrict__ stab)
{
    int idx = blockIdx.x * blockDim.x + threadIdx.x;   // TT*32 threads
    int t = idx >> 5;
    int i = idx & 31;
    float ex   = (2.0f * (float)i) / 64.0f;
    float invf = powf(10000.0f, -ex);
    float ang  = (float)t * invf;
    ctab[idx] = cosf(ang);
    stab[idx] = sinf(ang);
}

// ======================= projection GEMM =======================
// Y[b,o,t] = bias[o] + sum_c W[o,c] * X[b,c,t]
// 64x64 tile, BK=16, 256 threads, 4x4 per thread, fp32 VALU.
// MODE 0: plain store
// MODE 1: RoPE epilogue (tile = exactly one head since BM==D==64)
// MODE 2: Y[..] = sqrt(t_norm) * val            (local ctx into d_out)
// MODE 3: Y[..] = sqrt(1-t_norm) * val + Y[..]  (global ctx mixed into d_out)
template<int MODE>
__global__ __launch_bounds__(256)
void proj_kernel(const float* __restrict__ Wm, const float* __restrict__ bias,
                 const float* __restrict__ X, float* __restrict__ Y,
                 const float* __restrict__ ctab, const float* __restrict__ stab,
                 const int* __restrict__ tarr)
{
    __shared__ float Ws[16][68];   // [c][o], +4 pad: conflict-free + float4-aligned
    __shared__ float Xs[16][68];   // [c][t]
    const int tn0 = blockIdx.x * 64;
    const int om0 = blockIdx.y * 64;
    const int b   = blockIdx.z;
    const float* Xb = X + (size_t)b * CC * TT;
    const int tid = threadIdx.x;
    const int tx = tid & 15;       // t-quad
    const int ty = tid >> 4;       // o-quad

    const int wc4 = tid & 3;       // W load: float4 along c
    const int wo  = tid >> 2;
    const int xt4 = tid & 15;      // X load: float4 along t
    const int xc  = tid >> 4;

    float acc[4][4] = {};

    for (int k0 = 0; k0 < CC; k0 += 16) {
        float4 wv = *(const float4*)&Wm[(size_t)(om0 + wo) * CC + (k0 + wc4 * 4)];
        Ws[wc4 * 4 + 0][wo] = wv.x;
        Ws[wc4 * 4 + 1][wo] = wv.y;
        Ws[wc4 * 4 + 2][wo] = wv.z;
        Ws[wc4 * 4 + 3][wo] = wv.w;
        *(float4*)&Xs[xc][xt4 * 4] =
            *(const float4*)&Xb[(size_t)(k0 + xc) * TT + (tn0 + xt4 * 4)];
        __syncthreads();
        #pragma unroll
        for (int k = 0; k < 16; k++) {
            float4 av = *(const float4*)&Ws[k][ty * 4];
            float4 xv = *(const float4*)&Xs[k][tx * 4];
            float a[4] = {av.x, av.y, av.z, av.w};
            float c[4] = {xv.x, xv.y, xv.z, xv.w};
            #pragma unroll
            for (int i = 0; i < 4; i++)
                #pragma unroll
                for (int j = 0; j < 4; j++)
                    acc[i][j] = fmaf(a[i], c[j], acc[i][j]);
        }
        __syncthreads();
    }

    #pragma unroll
    for (int i = 0; i < 4; i++) {
        float bv = bias[om0 + ty * 4 + i];
        #pragma unroll
        for (int j = 0; j < 4; j++) acc[i][j] += bv;
    }

    if constexpr (MODE == 1) {
        // thread's 4 o's are consecutive => two complete RoPE pairs
        const int ip0 = ty * 2, ip1 = ty * 2 + 1;
        #pragma unroll
        for (int j = 0; j < 4; j++) {
            int t = tn0 + tx * 4 + j;
            float c0 = ctab[t * 32 + ip0], s0 = stab[t * 32 + ip0];
            float c1 = ctab[t * 32 + ip1], s1 = stab[t * 32 + ip1];
            float x1 = acc[0][j], x2 = acc[1][j];
            acc[0][j] = x1 * c0 - x2 * s0;
            acc[1][j] = x1 * s0 + x2 * c0;
            float y1 = acc[2][j], y2 = acc[3][j];
            acc[2][j] = y1 * c1 - y2 * s1;
            acc[3][j] = y1 * s1 + y2 * c1;
        }
    }

    float wmix = 1.0f;
    if constexpr (MODE == 2) wmix = sqrtf((float)tarr[b] / 999.0f);
    if constexpr (MODE == 3) wmix = sqrtf(1.0f - (float)tarr[b] / 999.0f);

    #pragma unroll
    for (int i = 0; i < 4; i++) {
        size_t base = ((size_t)b * CC + om0 + ty * 4 + i) * TT + tn0 + tx * 4;
        if constexpr (MODE <= 1) {
            *(float4*)&Y[base] = make_float4(acc[i][0], acc[i][1], acc[i][2], acc[i][3]);
        } else if constexpr (MODE == 2) {
            *(float4*)&Y[base] = make_float4(wmix * acc[i][0], wmix * acc[i][1],
                                             wmix * acc[i][2], wmix * acc[i][3]);
        } else {
            float4 prev = *(const float4*)&Y[base];
            *(float4*)&Y[base] = make_float4(fmaf(wmix, acc[i][0], prev.x),
                                             fmaf(wmix, acc[i][1], prev.y),
                                             fmaf(wmix, acc[i][2], prev.z),
                                             fmaf(wmix, acc[i][3], prev.w));
        }
    }
}

// ======================= local windowed attention =======================
// One thread per (b,h,t). Zero-padded (NOT masked) softmax over W=16.
// Output written with the reference's scrambled reshape:
//   A[b, h*64 + t/32, (t%32)*64 + d] = out(b,h,d,t)
__global__ __launch_bounds__(256)
void local_attn_kernel(const float* __restrict__ q, const float* __restrict__ k,
                       const float* __restrict__ v, float* __restrict__ out)
{
    int g  = blockIdx.x * blockDim.x + threadIdx.x;
    int t  = g & (TT - 1);
    int bh = g >> 11;
    int h  = bh & (HH - 1);
    int b  = bh >> 3;
    size_t base = ((size_t)b * CC + h * DD) * TT;
    const float* qp = q + base + t;

    int   koff[WLOC];
    float msk[WLOC];
    #pragma unroll
    for (int w = 0; w < WLOC; w++) {
        int kidx = t + w - 8;
        msk[w]  = (kidx >= 0 && kidx < TT) ? 1.0f : 0.0f;
        koff[w] = min(max(kidx, 0), TT - 1);
    }

    float dots[WLOC];
    #pragma unroll
    for (int w = 0; w < WLOC; w++) dots[w] = 0.0f;

    for (int d = 0; d < DD; d++) {
        float qd = qp[(size_t)d * TT];
        const float* kd = k + base + (size_t)d * TT;
        #pragma unroll
        for (int w = 0; w < WLOC; w++)
            dots[w] = fmaf(qd, kd[koff[w]], dots[w]);
    }

    float m = -1e30f;
    #pragma unroll
    for (int w = 0; w < WLOC; w++) {
        dots[w] = dots[w] * SCALE * msk[w];   // OOB dots forced to exact 0
        m = fmaxf(m, dots[w]);
    }
    float p[WLOC], s = 0.0f;
    #pragma unroll
    for (int w = 0; w < WLOC; w++) { p[w] = __expf(dots[w] - m); s += p[w]; }
    float inv = 1.0f / s;
    #pragma unroll
    for (int w = 0; w < WLOC; w++) p[w] = p[w] * msk[w] * inv;  // OOB v contributes 0

    // scrambled store (reference's (B,H,T,D)->(B,C,T) reshape)
    float* op = out + ((size_t)b * CC + h * DD + (t >> 5)) * TT + (size_t)(t & 31) * DD;
    for (int d = 0; d < DD; d++) {
        const float* vd = v + base + (size_t)d * TT;
        float o = 0.0f;
        #pragma unroll
        for (int w = 0; w < WLOC; w++) o = fmaf(p[w], vd[koff[w]], o);
        op[d] = o;
    }
}

// ======================= global attention =======================
// One thread per query (b,h,t); online softmax over all 2048 keys.
// K/V addresses are wave-uniform (b,h from blockIdx; kk,d loop-uniform)
// => scalar-load eligible; q/out accesses coalesced along t.
__global__ __launch_bounds__(256)
void global_attn_kernel(const float* __restrict__ q, const float* __restrict__ k,
                        const float* __restrict__ v, float* __restrict__ out)
{
    const int t = blockIdx.x * blockDim.x + threadIdx.x;
    const int h = blockIdx.y, b = blockIdx.z;
    size_t base = ((size_t)b * CC + h * DD) * TT;
    const float* qp = q + base;
    const float* kp = k + base;
    const float* vp = v + base;

    float qr[DD];
    #pragma unroll
    for (int d = 0; d < DD; d++) qr[d] = qp[(size_t)d * TT + t] * SCALE;

    float acc[DD];
    #pragma unroll
    for (int d = 0; d < DD; d++) acc[d] = 0.0f;
    float m = -INFINITY, s = 0.0f;

    for (int kk = 0; kk < TT; kk++) {
        float d0 = 0.f, d1 = 0.f, d2 = 0.f, d3 = 0.f;
        #pragma unroll
        for (int d = 0; d < DD; d += 4) {
            d0 = fmaf(qr[d + 0], kp[(size_t)(d + 0) * TT + kk], d0);
            d1 = fmaf(qr[d + 1], kp[(size_t)(d + 1) * TT + kk], d1);
            d2 = fmaf(qr[d + 2], kp[(size_t)(d + 2) * TT + kk], d2);
            d3 = fmaf(qr[d + 3], kp[(size_t)(d + 3) * TT + kk], d3);
        }
        float dot = (d0 + d1) + (d2 + d3);
        if (dot <= m) {                       // common path: 1 FMA per d
            float p = __expf(dot - m);
            s += p;
            #pragma unroll
            for (int d = 0; d < DD; d++)
                acc[d] = fmaf(p, vp[(size_t)d * TT + kk], acc[d]);
        } else {                              // rare rescale path
            float corr = __expf(m - dot);
            s = fmaf(s, corr, 1.0f);
            m = dot;
            #pragma unroll
            for (int d = 0; d < DD; d++)
                acc[d] = fmaf(acc[d], corr, vp[(size_t)d * TT + kk]);
        }
    }
    float inv = 1.0f / s;
    #pragma unroll
    for (int d = 0; d < DD; d++)
        out[base + (size_t)d * TT + t] = acc[d] * inv;
}

// ======================= launch =======================
extern "C" void kernel_launch(void* const* d_in, const int* in_sizes, int n_in,
                              void* d_out, int out_size, void* d_ws, size_t ws_size,
                              hipStream_t stream)
{
    const float* x    = (const float*)d_in[0];
    const float* cond = (const float*)d_in[1];
    const int*   tarr = (const int*)d_in[2];
    const float* lq_w = (const float*)d_in[3];
    const float* lq_b = (const float*)d_in[4];
    const float* lk_w = (const float*)d_in[5];
    const float* lk_b = (const float*)d_in[6];
    const float* lv_w = (const float*)d_in[7];
    const float* lv_b = (const float*)d_in[8];
    const float* lo_w = (const float*)d_in[9];
    const float* lo_b = (const float*)d_in[10];
    const float* gq_w = (const float*)d_in[11];
    const float* gq_b = (const float*)d_in[12];
    const float* gk_w = (const float*)d_in[13];
    const float* gk_b = (const float*)d_in[14];
    const float* gv_w = (const float*)d_in[15];
    const float* gv_b = (const float*)d_in[16];
    const float* go_w = (const float*)d_in[17];
    const float* go_b = (const float*)d_in[18];
    float* out = (float*)d_out;

    const size_t N = (size_t)BB * CC * TT;
    float* qbuf = (float*)d_ws;
    float* kbuf = qbuf + N;
    float* vbuf = kbuf + N;
    float* abuf = vbuf + N;
    float* ctab = abuf + N;
    float* stab = ctab + (size_t)TT * 32;

    dim3 pgrid(TT / 64, CC / 64, BB);
    dim3 pblk(256);

    rope_table_kernel<<<dim3(TT * 32 / 256), pblk, 0, stream>>>(ctab, stab);

    // ---- local branch ----
    proj_kernel<0><<<pgrid, pblk, 0, stream>>>(lq_w, lq_b, x,    qbuf, nullptr, nullptr, nullptr);
    proj_kernel<0><<<pgrid, pblk, 0, stream>>>(lk_w, lk_b, cond, kbuf, nullptr, nullptr, nullptr);
    proj_kernel<0><<<pgrid, pblk, 0, stream>>>(lv_w, lv_b, cond, vbuf, nullptr, nullptr, nullptr);
    local_attn_kernel<<<dim3(BB * HH * TT / 256), pblk, 0, stream>>>(qbuf, kbuf, vbuf, abuf);
    proj_kernel<2><<<pgrid, pblk, 0, stream>>>(lo_w, lo_b, abuf, out, nullptr, nullptr, tarr);

    // ---- global branch ----
    proj_kernel<1><<<pgrid, pblk, 0, stream>>>(gq_w, gq_b, x,    qbuf, ctab, stab, nullptr);
    proj_kernel<1><<<pgrid, pblk, 0, stream>>>(gk_w, gk_b, cond, kbuf, ctab, stab, nullptr);
    proj_kernel<0><<<pgrid, pblk, 0, stream>>>(gv_w, gv_b, cond, vbuf, nullptr, nullptr, nullptr);
    global_attn_kernel<<<dim3(TT / 256, HH, BB), pblk, 0, stream>>>(qbuf, kbuf, vbuf, abuf);
    proj_kernel<3><<<pgrid, pblk, 0, stream>>>(go_w, go_b, abuf, out, nullptr, nullptr, tarr);
}

// Round 2
// 743.198 us; speedup vs baseline: 5.0850x; 5.0850x over previous
//
#include <hip/hip_runtime.h>
#include <hip/hip_bf16.h>
#include <math.h>

#define BB 4
#define CC 512
#define TT 2048
#define HH 8
#define DD 64
#define WLOC 16

static constexpr float SCALE = 0.125f;   // D^-0.5, D=64

typedef __attribute__((ext_vector_type(8))) short  short8;
typedef __attribute__((ext_vector_type(4))) float  f32x4;

// float -> bf16 RTN (values are finite normals here)
static __device__ inline ushort f2bf(float f) {
    uint u = __float_as_uint(f);
    uint r = (u + 0x7fffu + ((u >> 16) & 1u)) >> 16;
    return (ushort)r;
}

// ======================= RoPE cos/sin table =======================
__global__ void rope_table_kernel(float* __restrict__ ctab, float* __restrict__ stab)
{
    int idx = blockIdx.x * blockDim.x + threadIdx.x;   // TT*32 threads
    int t = idx >> 5;
    int i = idx & 31;
    float ex   = (2.0f * (float)i) / 64.0f;
    float invf = powf(10000.0f, -ex);
    float ang  = (float)t * invf;
    ctab[idx] = cosf(ang);
    stab[idx] = sinf(ang);
}

// ======================= projection GEMM =======================
// Y[b,o,t] = bias[o] + sum_c W[o,c] * X[b,c,t]
// MODE 0: fp32 store            MODE 2: out = sqrt(tn) * val (into d_out)
// MODE 3: out += sqrt(1-tn)*val MODE 4: bf16 store, RoPE + qscale
// MODE 5: bf16 store plain
template<int MODE>
__global__ __launch_bounds__(256)
void proj_kernel(const float* __restrict__ Wm, const float* __restrict__ bias,
                 const float* __restrict__ X, float* __restrict__ Y,
                 const float* __restrict__ ctab, const float* __restrict__ stab,
                 const int* __restrict__ tarr, float qscale)
{
    __shared__ float Ws[16][68];
    __shared__ float Xs[16][68];
    const int tn0 = blockIdx.x * 64;
    const int om0 = blockIdx.y * 64;
    const int b   = blockIdx.z;
    const float* Xb = X + (size_t)b * CC * TT;
    const int tid = threadIdx.x;
    const int tx = tid & 15;
    const int ty = tid >> 4;

    const int wc4 = tid & 3;
    const int wo  = tid >> 2;
    const int xt4 = tid & 15;
    const int xc  = tid >> 4;

    float acc[4][4] = {};

    for (int k0 = 0; k0 < CC; k0 += 16) {
        float4 wv = *(const float4*)&Wm[(size_t)(om0 + wo) * CC + (k0 + wc4 * 4)];
        Ws[wc4 * 4 + 0][wo] = wv.x;
        Ws[wc4 * 4 + 1][wo] = wv.y;
        Ws[wc4 * 4 + 2][wo] = wv.z;
        Ws[wc4 * 4 + 3][wo] = wv.w;
        *(float4*)&Xs[xc][xt4 * 4] =
            *(const float4*)&Xb[(size_t)(k0 + xc) * TT + (tn0 + xt4 * 4)];
        __syncthreads();
        #pragma unroll
        for (int k = 0; k < 16; k++) {
            float4 av = *(const float4*)&Ws[k][ty * 4];
            float4 xv = *(const float4*)&Xs[k][tx * 4];
            float a[4] = {av.x, av.y, av.z, av.w};
            float c[4] = {xv.x, xv.y, xv.z, xv.w};
            #pragma unroll
            for (int i = 0; i < 4; i++)
                #pragma unroll
                for (int j = 0; j < 4; j++)
                    acc[i][j] = fmaf(a[i], c[j], acc[i][j]);
        }
        __syncthreads();
    }

    #pragma unroll
    for (int i = 0; i < 4; i++) {
        float bv = bias[om0 + ty * 4 + i];
        #pragma unroll
        for (int j = 0; j < 4; j++) acc[i][j] += bv;
    }

    if constexpr (MODE == 4) {
        // RoPE epilogue: thread's 4 o's are consecutive => two complete pairs
        const int ip0 = ty * 2, ip1 = ty * 2 + 1;
        #pragma unroll
        for (int j = 0; j < 4; j++) {
            int t = tn0 + tx * 4 + j;
            float c0 = ctab[t * 32 + ip0], s0 = stab[t * 32 + ip0];
            float c1 = ctab[t * 32 + ip1], s1 = stab[t * 32 + ip1];
            float x1 = acc[0][j], x2 = acc[1][j];
            acc[0][j] = (x1 * c0 - x2 * s0) * qscale;
            acc[1][j] = (x1 * s0 + x2 * c0) * qscale;
            float y1 = acc[2][j], y2 = acc[3][j];
            acc[2][j] = (y1 * c1 - y2 * s1) * qscale;
            acc[3][j] = (y1 * s1 + y2 * c1) * qscale;
        }
    }

    float wmix = 1.0f;
    if constexpr (MODE == 2) wmix = sqrtf((float)tarr[b] / 999.0f);
    if constexpr (MODE == 3) wmix = sqrtf(1.0f - (float)tarr[b] / 999.0f);

    #pragma unroll
    for (int i = 0; i < 4; i++) {
        size_t base = ((size_t)b * CC + om0 + ty * 4 + i) * TT + tn0 + tx * 4;
        if constexpr (MODE == 0) {
            *(float4*)&Y[base] = make_float4(acc[i][0], acc[i][1], acc[i][2], acc[i][3]);
        } else if constexpr (MODE == 2) {
            *(float4*)&Y[base] = make_float4(wmix * acc[i][0], wmix * acc[i][1],
                                             wmix * acc[i][2], wmix * acc[i][3]);
        } else if constexpr (MODE == 3) {
            float4 prev = *(const float4*)&Y[base];
            *(float4*)&Y[base] = make_float4(fmaf(wmix, acc[i][0], prev.x),
                                             fmaf(wmix, acc[i][1], prev.y),
                                             fmaf(wmix, acc[i][2], prev.z),
                                             fmaf(wmix, acc[i][3], prev.w));
        } else {
            // bf16 store (MODE 4/5)
            ushort* Yh = (ushort*)Y;
            uint lo = (uint)f2bf(acc[i][0]) | ((uint)f2bf(acc[i][1]) << 16);
            uint hi = (uint)f2bf(acc[i][2]) | ((uint)f2bf(acc[i][3]) << 16);
            uint2 pk = make_uint2(lo, hi);
            *(uint2*)&Yh[base] = pk;
        }
    }
}

// ======================= local windowed attention =======================
__global__ __launch_bounds__(256)
void local_attn_kernel(const float* __restrict__ q, const float* __restrict__ k,
                       const float* __restrict__ v, float* __restrict__ out)
{
    int g  = blockIdx.x * blockDim.x + threadIdx.x;
    int t  = g & (TT - 1);
    int bh = g >> 11;
    int h  = bh & (HH - 1);
    int b  = bh >> 3;
    size_t base = ((size_t)b * CC + h * DD) * TT;
    const float* qp = q + base + t;

    int   koff[WLOC];
    float msk[WLOC];
    #pragma unroll
    for (int w = 0; w < WLOC; w++) {
        int kidx = t + w - 8;
        msk[w]  = (kidx >= 0 && kidx < TT) ? 1.0f : 0.0f;
        koff[w] = min(max(kidx, 0), TT - 1);
    }

    float dots[WLOC];
    #pragma unroll
    for (int w = 0; w < WLOC; w++) dots[w] = 0.0f;

    for (int d = 0; d < DD; d++) {
        float qd = qp[(size_t)d * TT];
        const float* kd = k + base + (size_t)d * TT;
        #pragma unroll
        for (int w = 0; w < WLOC; w++)
            dots[w] = fmaf(qd, kd[koff[w]], dots[w]);
    }

    float m = -1e30f;
    #pragma unroll
    for (int w = 0; w < WLOC; w++) {
        dots[w] = dots[w] * SCALE * msk[w];
        m = fmaxf(m, dots[w]);
    }
    float p[WLOC], s = 0.0f;
    #pragma unroll
    for (int w = 0; w < WLOC; w++) { p[w] = __expf(dots[w] - m); s += p[w]; }
    float inv = 1.0f / s;
    #pragma unroll
    for (int w = 0; w < WLOC; w++) p[w] = p[w] * msk[w] * inv;

    float* op = out + ((size_t)b * CC + h * DD + (t >> 5)) * TT + (size_t)(t & 31) * DD;
    for (int d = 0; d < DD; d++) {
        const float* vd = v + base + (size_t)d * TT;
        float o = 0.0f;
        #pragma unroll
        for (int w = 0; w < WLOC; w++) o = fmaf(p[w], vd[koff[w]], o);
        op[d] = o;
    }
}

// ======================= global flash attention (bf16 MFMA) =======================
// Inputs q,k,v: bf16 [B, C, T] (d-major per head); q pre-scaled by 0.125, RoPE'd.
// Block: 256 threads (4 waves), 64 queries; loops 32 K-tiles of 64 keys.
// Per wave: 16 queries. S = QK^T via mfma(A=Q, B=K^T); out^T = V^T P^T.
__global__ __launch_bounds__(256)
void flash_global_kernel(const ushort* __restrict__ qb, const ushort* __restrict__ kb,
                         const ushort* __restrict__ vb, float* __restrict__ out)
{
    __shared__ __align__(16) ushort Ks[64][64];  // [tk][d ^ ((tk&7)<<3)]
    __shared__ __align__(16) ushort Vs[64][64];  // [d][tk ^ ((d&7)<<3)]
    __shared__ __align__(16) ushort Ps[64][64];  // [k][16*wid + (q ^ (k&15))]

    const int tid  = threadIdx.x;
    const int wid  = tid >> 6;
    const int lane = tid & 63;
    const int x    = lane & 15;
    const int g    = lane >> 4;

    const int q0 = blockIdx.x * 64;
    const int h  = blockIdx.y;
    const int b  = blockIdx.z;
    const size_t bh_off = ((size_t)b * CC + h * DD) * TT;
    const ushort* qbh = qb + bh_off;
    const ushort* kbh = kb + bh_off;
    const ushort* vbh = vb + bh_off;

    const int q_glob = q0 + wid * 16 + x;

    // ---- Q fragments (persistent, direct from global) ----
    short8 aQ[2];
    #pragma unroll
    for (int kap = 0; kap < 2; kap++)
        #pragma unroll
        for (int j = 0; j < 8; j++)
            aQ[kap][j] = (short)qbh[(size_t)(kap * 32 + g * 8 + j) * TT + q_glob];

    f32x4 oacc[4];
    #pragma unroll
    for (int d = 0; d < 4; d++) oacc[d] = (f32x4){0.f, 0.f, 0.f, 0.f};
    float m_run[4], l_run[4];
    #pragma unroll
    for (int r = 0; r < 4; r++) { m_run[r] = -INFINITY; l_run[r] = 0.0f; }

    const int tk_l = tid & 63;       // K staging: thread's key index
    const int pp   = tid & 31;       // V staging: thread's t-pair

    for (int kt = 0; kt < 32; kt++) {
        const int kt0 = kt * 64;
        __syncthreads();   // previous tile's LDS reads complete

        // ---- stage K transposed: Ks[tk][d], swizzle d ^ ((tk&7)<<3) ----
        #pragma unroll
        for (int dp = 0; dp < 8; dp++) {
            int dpi = (tid >> 6) + dp * 4;          // 0..31
            int d = dpi * 2;
            ushort u0 = kbh[(size_t)d       * TT + kt0 + tk_l];
            ushort u1 = kbh[(size_t)(d + 1) * TT + kt0 + tk_l];
            uint val = (uint)u0 | ((uint)u1 << 16);
            int col = d ^ ((tk_l & 7) << 3);
            *(uint*)&Ks[tk_l][col] = val;
        }
        // ---- stage V natural: Vs[d][tk], swizzle tk ^ ((d&7)<<3) ----
        #pragma unroll
        for (int dp = 0; dp < 8; dp++) {
            int d = (tid >> 5) + dp * 8;            // 0..63
            uint val = *(const uint*)&vbh[(size_t)d * TT + kt0 + pp * 2];
            int col = (pp * 2) ^ ((d & 7) << 3);
            *(uint*)&Vs[d][col] = val;
        }
        __syncthreads();

        // ---- S = Q K^T  (C-layout: lane holds S[q=4g+r][k=16tau+x]) ----
        f32x4 S[4];
        #pragma unroll
        for (int tau = 0; tau < 4; tau++) S[tau] = (f32x4){0.f, 0.f, 0.f, 0.f};
        #pragma unroll
        for (int kap = 0; kap < 2; kap++)
            #pragma unroll
            for (int tau = 0; tau < 4; tau++) {
                int row = tau * 16 + x;
                int col = (kap * 32 + g * 8) ^ ((x & 7) << 3);
                short8 bK = *(short8*)&Ks[row][col];
                S[tau] = __builtin_amdgcn_mfma_f32_16x16x32_bf16(aQ[kap], bK, S[tau], 0, 0, 0);
            }

        // ---- online softmax ----
        float mr[4];
        #pragma unroll
        for (int r = 0; r < 4; r++)
            mr[r] = fmaxf(fmaxf(S[0][r], S[1][r]), fmaxf(S[2][r], S[3][r]));
        #pragma unroll
        for (int msk = 1; msk <= 8; msk <<= 1)
            #pragma unroll
            for (int r = 0; r < 4; r++)
                mr[r] = fmaxf(mr[r], __shfl_xor(mr[r], msk));

        float corr[4];
        float P[4][4];
        float sm[4];
        #pragma unroll
        for (int r = 0; r < 4; r++) {
            float mnew = fmaxf(m_run[r], mr[r]);
            corr[r] = __expf(m_run[r] - mnew);
            m_run[r] = mnew;
            float s0 = __expf(S[0][r] - mnew);
            float s1 = __expf(S[1][r] - mnew);
            float s2 = __expf(S[2][r] - mnew);
            float s3 = __expf(S[3][r] - mnew);
            P[0][r] = s0; P[1][r] = s1; P[2][r] = s2; P[3][r] = s3;
            sm[r] = (s0 + s1) + (s2 + s3);
        }
        #pragma unroll
        for (int msk = 1; msk <= 8; msk <<= 1)
            #pragma unroll
            for (int r = 0; r < 4; r++)
                sm[r] += __shfl_xor(sm[r], msk);
        #pragma unroll
        for (int r = 0; r < 4; r++)
            l_run[r] = l_run[r] * corr[r] + sm[r];

        // ---- P -> LDS (wave-private columns) ----
        #pragma unroll
        for (int tau = 0; tau < 4; tau++)
            #pragma unroll
            for (int r = 0; r < 4; r++) {
                int k_loc = tau * 16 + x;
                int col = wid * 16 + ((g * 4 + r) ^ x);
                Ps[k_loc][col] = f2bf(P[tau][r]);
            }

        // ---- rescale out-acc: cf for q-col = x ----
        {
            float t0 = __shfl(corr[0], (x >> 2) << 4);
            float t1 = __shfl(corr[1], (x >> 2) << 4);
            float t2 = __shfl(corr[2], (x >> 2) << 4);
            float t3 = __shfl(corr[3], (x >> 2) << 4);
            float s01 = (x & 1) ? t1 : t0;
            float s23 = (x & 1) ? t3 : t2;
            float cf  = (x & 2) ? s23 : s01;
            #pragma unroll
            for (int d = 0; d < 4; d++) {
                oacc[d][0] *= cf; oacc[d][1] *= cf;
                oacc[d][2] *= cf; oacc[d][3] *= cf;
            }
        }

        // ---- PV: out^T += V^T P^T ----
        short8 bP[2];
        #pragma unroll
        for (int kap = 0; kap < 2; kap++)
            #pragma unroll
            for (int j = 0; j < 8; j++) {
                int k_loc = kap * 32 + g * 8 + j;
                int col = wid * 16 + (x ^ (k_loc & 15));
                bP[kap][j] = (short)Ps[k_loc][col];
            }
        #pragma unroll
        for (int dlt = 0; dlt < 4; dlt++)
            #pragma unroll
            for (int kap = 0; kap < 2; kap++) {
                int row = dlt * 16 + x;
                int col = (kap * 32 + g * 8) ^ ((x & 7) << 3);
                short8 aV = *(short8*)&Vs[row][col];
                oacc[dlt] = __builtin_amdgcn_mfma_f32_16x16x32_bf16(aV, bP[kap], oacc[dlt], 0, 0, 0);
            }
    }

    // ---- final normalize + store out^T[d][q] ----
    float t0 = __shfl(l_run[0], (x >> 2) << 4);
    float t1 = __shfl(l_run[1], (x >> 2) << 4);
    float t2 = __shfl(l_run[2], (x >> 2) << 4);
    float t3 = __shfl(l_run[3], (x >> 2) << 4);
    float s01 = (x & 1) ? t1 : t0;
    float s23 = (x & 1) ? t3 : t2;
    float lf  = (x & 2) ? s23 : s01;
    float inv = 1.0f / lf;

    #pragma unroll
    for (int dlt = 0; dlt < 4; dlt++)
        #pragma unroll
        for (int r = 0; r < 4; r++) {
            int d = dlt * 16 + g * 4 + r;
            out[bh_off + (size_t)d * TT + q_glob] = oacc[dlt][r] * inv;
        }
}

// ======================= launch =======================
extern "C" void kernel_launch(void* const* d_in, const int* in_sizes, int n_in,
                              void* d_out, int out_size, void* d_ws, size_t ws_size,
                              hipStream_t stream)
{
    const float* x    = (const float*)d_in[0];
    const float* cond = (const float*)d_in[1];
    const int*   tarr = (const int*)d_in[2];
    const float* lq_w = (const float*)d_in[3];
    const float* lq_b = (const float*)d_in[4];
    const float* lk_w = (const float*)d_in[5];
    const float* lk_b = (const float*)d_in[6];
    const float* lv_w = (const float*)d_in[7];
    const float* lv_b = (const float*)d_in[8];
    const float* lo_w = (const float*)d_in[9];
    const float* lo_b = (const float*)d_in[10];
    const float* gq_w = (const float*)d_in[11];
    const float* gq_b = (const float*)d_in[12];
    const float* gk_w = (const float*)d_in[13];
    const float* gk_b = (const float*)d_in[14];
    const float* gv_w = (const float*)d_in[15];
    const float* gv_b = (const float*)d_in[16];
    const float* go_w = (const float*)d_in[17];
    const float* go_b = (const float*)d_in[18];
    float* out = (float*)d_out;

    const size_t N = (size_t)BB * CC * TT;
    float* qbuf = (float*)d_ws;
    float* kbuf = qbuf + N;
    float* vbuf = kbuf + N;
    float* abuf = vbuf + N;
    float* ctab = abuf + N;
    float* stab = ctab + (size_t)TT * 32;

    dim3 pgrid(TT / 64, CC / 64, BB);
    dim3 pblk(256);

    rope_table_kernel<<<dim3(TT * 32 / 256), pblk, 0, stream>>>(ctab, stab);

    // ---- local branch (fp32) ----
    proj_kernel<0><<<pgrid, pblk, 0, stream>>>(lq_w, lq_b, x,    qbuf, nullptr, nullptr, nullptr, 1.f);
    proj_kernel<0><<<pgrid, pblk, 0, stream>>>(lk_w, lk_b, cond, kbuf, nullptr, nullptr, nullptr, 1.f);
    proj_kernel<0><<<pgrid, pblk, 0, stream>>>(lv_w, lv_b, cond, vbuf, nullptr, nullptr, nullptr, 1.f);
    local_attn_kernel<<<dim3(BB * HH * TT / 256), pblk, 0, stream>>>(qbuf, kbuf, vbuf, abuf);
    proj_kernel<2><<<pgrid, pblk, 0, stream>>>(lo_w, lo_b, abuf, out, nullptr, nullptr, tarr, 1.f);

    // ---- global branch (bf16 MFMA flash) ----
    // bf16 q/k/v alias the now-free fp32 buffers
    ushort* qb = (ushort*)qbuf;
    ushort* kb = (ushort*)kbuf;
    ushort* vb = (ushort*)vbuf;
    proj_kernel<4><<<pgrid, pblk, 0, stream>>>(gq_w, gq_b, x,    (float*)qb, ctab, stab, nullptr, SCALE);
    proj_kernel<4><<<pgrid, pblk, 0, stream>>>(gk_w, gk_b, cond, (float*)kb, ctab, stab, nullptr, 1.0f);
    proj_kernel<5><<<pgrid, pblk, 0, stream>>>(gv_w, gv_b, cond, (float*)vb, nullptr, nullptr, nullptr, 1.f);
    flash_global_kernel<<<dim3(TT / 64, HH, BB), pblk, 0, stream>>>(qb, kb, vb, abuf);
    proj_kernel<3><<<pgrid, pblk, 0, stream>>>(go_w, go_b, abuf, out, nullptr, nullptr, tarr, 1.f);
}

// Round 3
// 318.815 us; speedup vs baseline: 11.8539x; 2.3311x over previous
//
#include <hip/hip_runtime.h>
#include <math.h>

#define BB 4
#define CC 512
#define TT 2048
#define HH 8
#define DD 64

static constexpr float SCALE = 0.125f;   // D^-0.5, D=64

typedef __attribute__((ext_vector_type(8))) short  short8;
typedef __attribute__((ext_vector_type(4))) float  f32x4;

static __device__ __forceinline__ ushort f2bf(float f) {
    uint u = __float_as_uint(f);
    uint r = (u + 0x7fffu + ((u >> 16) & 1u)) >> 16;
    return (ushort)r;
}
static __device__ __forceinline__ float bf2f(ushort u) {
    return __uint_as_float((uint)u << 16);
}

typedef unsigned int u32;
typedef u32 __attribute__((address_space(1))) gu32;
typedef u32 __attribute__((address_space(3))) lu32;
static __device__ __forceinline__ void gload_lds16(const void* g, void* l) {
    __builtin_amdgcn_global_load_lds((const gu32*)g, (lu32*)l, 16, 0, 0);
}

// ======================= RoPE cos/sin table, [i][t] layout =======================
__global__ void rope_table_kernel(float* __restrict__ ctab, float* __restrict__ stab)
{
    int idx = blockIdx.x * blockDim.x + threadIdx.x;   // 32*2048 threads
    int i = idx >> 11;
    int t = idx & 2047;
    float ex   = (2.0f * (float)i) / 64.0f;
    float invf = powf(10000.0f, -ex);
    float ang  = (float)t * invf;
    ctab[idx] = cosf(ang);
    stab[idx] = sinf(ang);
}

// ======================= weight fp32 -> bf16 =======================
__global__ void wcvt_kernel(const float* w0, const float* w1, const float* w2, const float* w3,
                            const float* w4, const float* w5, const float* w6, const float* w7,
                            ushort* __restrict__ dst)
{
    const float* srcs[8] = {w0, w1, w2, w3, w4, w5, w6, w7};
    int wi = blockIdx.y;
    int idx = (blockIdx.x * 256 + threadIdx.x) * 4;
    float4 v = *(const float4*)&srcs[wi][idx];
    uint lo = (uint)f2bf(v.x) | ((uint)f2bf(v.y) << 16);
    uint hi = (uint)f2bf(v.z) | ((uint)f2bf(v.w) << 16);
    *(uint2*)&dst[(size_t)wi * 262144 + idx] = make_uint2(lo, hi);
}

// ======================= transpose [b][c][t] -> bf16 [b][t][c] =======================
__global__ __launch_bounds__(256)
void transpose_f32_kernel(const float* __restrict__ in, ushort* __restrict__ outp)
{
    __shared__ ushort L[64][66];
    const int t0 = blockIdx.x * 64, c0 = blockIdx.y * 64, b = blockIdx.z;
    const float* inb = in + (size_t)b * CC * TT;
    ushort* outb = outp + (size_t)b * TT * CC;
    const int lc = threadIdx.x >> 6;     // 0..3
    const int lt = threadIdx.x & 63;
    #pragma unroll
    for (int i = 0; i < 16; i++) {
        int c = i * 4 + lc;
        L[c][lt] = f2bf(inb[(size_t)(c0 + c) * TT + t0 + lt]);
    }
    __syncthreads();
    #pragma unroll
    for (int i = 0; i < 16; i++) {
        int t = i * 4 + lc;
        outb[(size_t)(t0 + t) * CC + c0 + lt] = L[lt][t];
    }
}

__global__ __launch_bounds__(256)
void transpose_bf16_kernel(const ushort* __restrict__ in, ushort* __restrict__ outp)
{
    __shared__ ushort L[64][66];
    const int t0 = blockIdx.x * 64, c0 = blockIdx.y * 64, b = blockIdx.z;
    const ushort* inb = in + (size_t)b * CC * TT;
    ushort* outb = outp + (size_t)b * TT * CC;
    const int lc = threadIdx.x >> 6;
    const int lt = threadIdx.x & 63;
    #pragma unroll
    for (int i = 0; i < 16; i++) {
        int c = i * 4 + lc;
        L[c][lt] = inb[(size_t)(c0 + c) * TT + t0 + lt];
    }
    __syncthreads();
    #pragma unroll
    for (int i = 0; i < 16; i++) {
        int t = i * 4 + lc;
        outb[(size_t)(t0 + t) * CC + c0 + lt] = L[lt][t];
    }
}

// ======================= MFMA projection GEMM =======================
// C[m=512][n=8192(b*t)] = Wbf[m][k=512] . XT[n][k]   (+ bias, epilogue MODE)
// 128x128 tile, BK=32, 256 threads (4 waves 2x2, each 64x64), global_load_lds staging.
// MODE 0: bf16 C^T store to [n][m]          (local q/k/v -> [b][t][c])
// MODE 1: MODE 0 + RoPE + qscale            (global q/k)
// MODE 2: bf16 C natural [b][c][t]          (global v)
// MODE 3: fp32 d_out = sqrt(tn)*val         (local out-proj)
// MODE 4: fp32 d_out += sqrt(1-tn)*val      (global out-proj)
template<int MODE>
__global__ __launch_bounds__(256)
void gemm_kernel(const ushort* __restrict__ Wbf, const float* __restrict__ bias,
                 const ushort* __restrict__ XT, void* __restrict__ Yv,
                 const float* __restrict__ ctab, const float* __restrict__ stab,
                 const int* __restrict__ tarr, float qscale)
{
    __shared__ __align__(16) ushort As[2][128][32];
    __shared__ __align__(16) ushort Bs[2][128][32];
    const int tid  = threadIdx.x;
    const int wid  = tid >> 6;
    const int lane = tid & 63;
    const int x  = lane & 15;
    const int gq = lane >> 4;
    const int wm = wid >> 1, wn = wid & 1;
    const int m0 = blockIdx.y * 128;
    const int n0 = blockIdx.x * 128;

    const int srow = lane >> 2;       // 0..15 (row within wave's 16-row chunk)
    const int sblk = lane & 3;        // 16B block position

    f32x4 acc[4][4];
    #pragma unroll
    for (int i = 0; i < 4; i++)
        #pragma unroll
        for (int j = 0; j < 4; j++) acc[i][j] = (f32x4){0.f, 0.f, 0.f, 0.f};

    auto stage = [&](int bf, int k0) {
        #pragma unroll
        for (int c = 0; c < 2; c++) {
            int row = c * 64 + wid * 16 + srow;           // 0..127
            int db  = sblk ^ ((row >> 1) & 3);            // source data block
            gload_lds16(&Wbf[(size_t)(m0 + row) * 512 + k0 + db * 8],
                        &As[bf][c * 64 + wid * 16][0]);
            gload_lds16(&XT [(size_t)(n0 + row) * 512 + k0 + db * 8],
                        &Bs[bf][c * 64 + wid * 16][0]);
        }
    };

    stage(0, 0);
    __syncthreads();

    for (int ks = 0; ks < 16; ks++) {
        int cur = ks & 1;
        if (ks < 15) stage(cur ^ 1, (ks + 1) * 32);
        short8 aF[4], bF[4];
        #pragma unroll
        for (int mi = 0; mi < 4; mi++) {
            int row = wm * 64 + mi * 16 + x;
            aF[mi] = *(const short8*)&As[cur][row][(gq ^ ((row >> 1) & 3)) * 8];
        }
        #pragma unroll
        for (int nj = 0; nj < 4; nj++) {
            int row = wn * 64 + nj * 16 + x;
            bF[nj] = *(const short8*)&Bs[cur][row][(gq ^ ((row >> 1) & 3)) * 8];
        }
        #pragma unroll
        for (int mi = 0; mi < 4; mi++)
            #pragma unroll
            for (int nj = 0; nj < 4; nj++)
                acc[mi][nj] = __builtin_amdgcn_mfma_f32_16x16x32_bf16(aF[mi], bF[nj], acc[mi][nj], 0, 0, 0);
        __syncthreads();
    }

    const int bidx = (n0 + wn * 64) >> 11;     // batch (wave-uniform)
    float wl = 1.0f;
    if constexpr (MODE == 3) wl = sqrtf((float)tarr[bidx] / 999.0f);
    if constexpr (MODE == 4) wl = sqrtf(1.0f - (float)tarr[bidx] / 999.0f);

    #pragma unroll
    for (int mi = 0; mi < 4; mi++) {
        const int mb = m0 + wm * 64 + mi * 16 + 4 * gq;   // 4 consecutive m
        float bv[4];
        #pragma unroll
        for (int r = 0; r < 4; r++) bv[r] = bias[mb + r];
        #pragma unroll
        for (int nj = 0; nj < 4; nj++) {
            const int n  = n0 + wn * 64 + nj * 16 + x;
            const int tt = n & 2047;
            f32x4 v = acc[mi][nj];
            v[0] += bv[0]; v[1] += bv[1]; v[2] += bv[2]; v[3] += bv[3];
            if constexpr (MODE == 1) {
                const int i0 = (mb & 63) >> 1;            // rope pair index (8mi+2g)
                float c0 = ctab[(size_t)i0 * 2048 + tt],       s0 = stab[(size_t)i0 * 2048 + tt];
                float c1 = ctab[(size_t)(i0 + 1) * 2048 + tt], s1 = stab[(size_t)(i0 + 1) * 2048 + tt];
                float e0 = (v[0] * c0 - v[1] * s0) * qscale;
                float e1 = (v[0] * s0 + v[1] * c0) * qscale;
                float e2 = (v[2] * c1 - v[3] * s1) * qscale;
                float e3 = (v[2] * s1 + v[3] * c1) * qscale;
                v[0] = e0; v[1] = e1; v[2] = e2; v[3] = e3;
            }
            if constexpr (MODE == 0 || MODE == 1) {
                ushort* Y = (ushort*)Yv;
                uint lo = (uint)f2bf(v[0]) | ((uint)f2bf(v[1]) << 16);
                uint hi = (uint)f2bf(v[2]) | ((uint)f2bf(v[3]) << 16);
                *(uint2*)&Y[(size_t)n * 512 + mb] = make_uint2(lo, hi);
            } else if constexpr (MODE == 2) {
                ushort* Y = (ushort*)Yv;
                #pragma unroll
                for (int r = 0; r < 4; r++)
                    Y[((size_t)bidx * 512 + mb + r) * 2048 + tt] = f2bf(v[r]);
            } else if constexpr (MODE == 3) {
                float* Y = (float*)Yv;
                #pragma unroll
                for (int r = 0; r < 4; r++)
                    Y[((size_t)bidx * 512 + mb + r) * 2048 + tt] = wl * v[r];
            } else {
                float* Y = (float*)Yv;
                #pragma unroll
                for (int r = 0; r < 4; r++) {
                    size_t a = ((size_t)bidx * 512 + mb + r) * 2048 + tt;
                    Y[a] = fmaf(wl, v[r], Y[a]);
                }
            }
        }
    }
}

// ======================= local windowed attention (bf16 [t][c] in) =======================
__global__ __launch_bounds__(256)
void local_attn_kernel(const ushort* __restrict__ qt, const ushort* __restrict__ kt,
                       const ushort* __restrict__ vt, ushort* __restrict__ outb)
{
    int gidx = blockIdx.x * 256 + threadIdx.x;
    int t  = gidx & (TT - 1);
    int bh = gidx >> 11;
    int h  = bh & (HH - 1);
    int b  = bh >> 3;
    const size_t rb = (size_t)b * TT;
    const int co = h * DD;

    float qf[64];
    {
        const ushort* qp = qt + (rb + t) * 512 + co;
        #pragma unroll
        for (int i = 0; i < 8; i++) {
            short8 v = *(const short8*)&qp[i * 8];
            #pragma unroll
            for (int j = 0; j < 8; j++) qf[i * 8 + j] = bf2f((ushort)v[j]);
        }
    }

    int koff[16]; float msk[16];
    #pragma unroll
    for (int w = 0; w < 16; w++) {
        int kidx = t + w - 8;
        msk[w]  = (kidx >= 0 && kidx < TT) ? 1.0f : 0.0f;
        koff[w] = min(max(kidx, 0), TT - 1);
    }

    float dots[16];
    #pragma unroll
    for (int w = 0; w < 16; w++) {
        const ushort* kp = kt + (rb + koff[w]) * 512 + co;
        float d0 = 0.f, d1 = 0.f;
        #pragma unroll
        for (int i = 0; i < 8; i++) {
            short8 v = *(const short8*)&kp[i * 8];
            #pragma unroll
            for (int j = 0; j < 8; j += 2) {
                d0 = fmaf(qf[i * 8 + j],     bf2f((ushort)v[j]),     d0);
                d1 = fmaf(qf[i * 8 + j + 1], bf2f((ushort)v[j + 1]), d1);
            }
        }
        dots[w] = d0 + d1;
    }

    float m = -1e30f;
    #pragma unroll
    for (int w = 0; w < 16; w++) { dots[w] = dots[w] * SCALE * msk[w]; m = fmaxf(m, dots[w]); }
    float p[16], s = 0.f;
    #pragma unroll
    for (int w = 0; w < 16; w++) { p[w] = __expf(dots[w] - m); s += p[w]; }
    float inv = 1.0f / s;
    #pragma unroll
    for (int w = 0; w < 16; w++) p[w] *= msk[w] * inv;

    float oa[64];
    #pragma unroll
    for (int d = 0; d < 64; d++) oa[d] = 0.f;
    #pragma unroll
    for (int w = 0; w < 16; w++) {
        const ushort* vp = vt + (rb + koff[w]) * 512 + co;
        #pragma unroll
        for (int i = 0; i < 8; i++) {
            short8 v = *(const short8*)&vp[i * 8];
            #pragma unroll
            for (int j = 0; j < 8; j++)
                oa[i * 8 + j] = fmaf(p[w], bf2f((ushort)v[j]), oa[i * 8 + j]);
        }
    }

    // scrambled store (reference's (B,H,T,D)->(B,C,T) reshape), bf16 [c'][t']
    ushort* op = outb + ((size_t)b * CC + co + (t >> 5)) * TT + (size_t)(t & 31) * DD;
    #pragma unroll
    for (int i = 0; i < 16; i++) {
        uint lo = (uint)f2bf(oa[i * 4 + 0]) | ((uint)f2bf(oa[i * 4 + 1]) << 16);
        uint hi = (uint)f2bf(oa[i * 4 + 2]) | ((uint)f2bf(oa[i * 4 + 3]) << 16);
        *(uint2*)&op[i * 4] = make_uint2(lo, hi);
    }
}

// ======================= global flash attention (bf16 MFMA) =======================
// q,k: bf16 [b][t][c] (RoPE'd; q pre-scaled). v: bf16 [b][c][t]. out: bf16 [b][t][c].
__global__ __launch_bounds__(256)
void flash_global_kernel(const ushort* __restrict__ qtd, const ushort* __restrict__ ktd,
                         const ushort* __restrict__ vb, ushort* __restrict__ gb)
{
    __shared__ __align__(16) ushort Ks[64][64];  // [tk][d ^ ((tk&7)<<3)]
    __shared__ __align__(16) ushort Vs[64][64];  // [d][tk ^ ((d&7)<<3)]
    __shared__ __align__(16) ushort Ps[64][64];  // [k][16*wid + (q ^ (k&15))]

    const int tid  = threadIdx.x;
    const int wid  = tid >> 6;
    const int lane = tid & 63;
    const int x    = lane & 15;
    const int g    = lane >> 4;

    const int q0 = blockIdx.x * 64;
    const int h  = blockIdx.y;
    const int b  = blockIdx.z;
    const size_t bh_ct = ((size_t)b * CC + h * DD) * TT;   // v [b][c][t]
    const size_t btd   = (size_t)b * TT;                   // [b][t][c] row base
    const ushort* vbh = vb + bh_ct;

    const int q_glob = q0 + wid * 16 + x;

    // ---- Q fragments: contiguous 16B from [t][d] ----
    short8 aQ[2];
    {
        const ushort* qrow = qtd + (btd + q_glob) * 512 + h * 64;
        aQ[0] = *(const short8*)&qrow[g * 8];
        aQ[1] = *(const short8*)&qrow[32 + g * 8];
    }

    f32x4 oacc[4];
    #pragma unroll
    for (int d = 0; d < 4; d++) oacc[d] = (f32x4){0.f, 0.f, 0.f, 0.f};
    float m_run[4], l_run[4];
    #pragma unroll
    for (int r = 0; r < 4; r++) { m_run[r] = -INFINITY; l_run[r] = 0.0f; }

    const int pp = tid & 31;          // V staging t-pair

    for (int kt = 0; kt < 32; kt++) {
        const int kt0 = kt * 64;
        __syncthreads();   // previous tile's LDS reads complete

        // ---- stage K: rows from [t][d], ds_write_b128, conflict-free ----
        #pragma unroll
        for (int half = 0; half < 2; half++) {
            int tk  = (tid >> 3) + half * 32;
            int db  = tid & 7;
            int pos = db ^ (tk & 7);
            short8 val = *(const short8*)&ktd[(btd + kt0 + tk) * 512 + h * 64 + db * 8];
            *(short8*)&Ks[tk][pos * 8] = val;
        }
        // ---- stage V natural: Vs[d][tk], swizzle tk ^ ((d&7)<<3) ----
        #pragma unroll
        for (int dp = 0; dp < 8; dp++) {
            int d = (tid >> 5) + dp * 8;            // 0..63
            uint val = *(const uint*)&vbh[(size_t)d * TT + kt0 + pp * 2];
            int col = (pp * 2) ^ ((d & 7) << 3);
            *(uint*)&Vs[d][col] = val;
        }
        __syncthreads();

        // ---- S = Q K^T  (C-layout: lane holds S[q=4g+r][k=16tau+x]) ----
        f32x4 S[4];
        #pragma unroll
        for (int tau = 0; tau < 4; tau++) S[tau] = (f32x4){0.f, 0.f, 0.f, 0.f};
        #pragma unroll
        for (int kap = 0; kap < 2; kap++)
            #pragma unroll
            for (int tau = 0; tau < 4; tau++) {
                int row = tau * 16 + x;
                int col = (kap * 32 + g * 8) ^ ((x & 7) << 3);
                short8 bK = *(const short8*)&Ks[row][col];
                S[tau] = __builtin_amdgcn_mfma_f32_16x16x32_bf16(aQ[kap], bK, S[tau], 0, 0, 0);
            }

        // ---- online softmax ----
        float mr[4];
        #pragma unroll
        for (int r = 0; r < 4; r++)
            mr[r] = fmaxf(fmaxf(S[0][r], S[1][r]), fmaxf(S[2][r], S[3][r]));
        #pragma unroll
        for (int msk = 1; msk <= 8; msk <<= 1)
            #pragma unroll
            for (int r = 0; r < 4; r++)
                mr[r] = fmaxf(mr[r], __shfl_xor(mr[r], msk));

        float corr[4];
        float P[4][4];
        float sm[4];
        #pragma unroll
        for (int r = 0; r < 4; r++) {
            float mnew = fmaxf(m_run[r], mr[r]);
            corr[r] = __expf(m_run[r] - mnew);
            m_run[r] = mnew;
            float s0 = __expf(S[0][r] - mnew);
            float s1 = __expf(S[1][r] - mnew);
            float s2 = __expf(S[2][r] - mnew);
            float s3 = __expf(S[3][r] - mnew);
            P[0][r] = s0; P[1][r] = s1; P[2][r] = s2; P[3][r] = s3;
            sm[r] = (s0 + s1) + (s2 + s3);
        }
        #pragma unroll
        for (int msk = 1; msk <= 8; msk <<= 1)
            #pragma unroll
            for (int r = 0; r < 4; r++)
                sm[r] += __shfl_xor(sm[r], msk);
        #pragma unroll
        for (int r = 0; r < 4; r++)
            l_run[r] = l_run[r] * corr[r] + sm[r];

        // ---- P -> LDS (wave-private columns) ----
        #pragma unroll
        for (int tau = 0; tau < 4; tau++)
            #pragma unroll
            for (int r = 0; r < 4; r++) {
                int k_loc = tau * 16 + x;
                int col = wid * 16 + ((g * 4 + r) ^ x);
                Ps[k_loc][col] = f2bf(P[tau][r]);
            }

        // ---- rescale out-acc: cf for q-col = x ----
        {
            float t0 = __shfl(corr[0], (x >> 2) << 4);
            float t1 = __shfl(corr[1], (x >> 2) << 4);
            float t2 = __shfl(corr[2], (x >> 2) << 4);
            float t3 = __shfl(corr[3], (x >> 2) << 4);
            float s01 = (x & 1) ? t1 : t0;
            float s23 = (x & 1) ? t3 : t2;
            float cf  = (x & 2) ? s23 : s01;
            #pragma unroll
            for (int d = 0; d < 4; d++) {
                oacc[d][0] *= cf; oacc[d][1] *= cf;
                oacc[d][2] *= cf; oacc[d][3] *= cf;
            }
        }

        // ---- PV: out^T += V^T P^T ----
        short8 bP[2];
        #pragma unroll
        for (int kap = 0; kap < 2; kap++)
            #pragma unroll
            for (int j = 0; j < 8; j++) {
                int k_loc = kap * 32 + g * 8 + j;
                int col = wid * 16 + (x ^ (k_loc & 15));
                bP[kap][j] = (short)Ps[k_loc][col];
            }
        #pragma unroll
        for (int dlt = 0; dlt < 4; dlt++)
            #pragma unroll
            for (int kap = 0; kap < 2; kap++) {
                int row = dlt * 16 + x;
                int col = (kap * 32 + g * 8) ^ ((x & 7) << 3);
                short8 aV = *(const short8*)&Vs[row][col];
                oacc[dlt] = __builtin_amdgcn_mfma_f32_16x16x32_bf16(aV, bP[kap], oacc[dlt], 0, 0, 0);
            }
    }

    // ---- final normalize + store bf16 [b][t][c] ----
    float t0 = __shfl(l_run[0], (x >> 2) << 4);
    float t1 = __shfl(l_run[1], (x >> 2) << 4);
    float t2 = __shfl(l_run[2], (x >> 2) << 4);
    float t3 = __shfl(l_run[3], (x >> 2) << 4);
    float s01 = (x & 1) ? t1 : t0;
    float s23 = (x & 1) ? t3 : t2;
    float lf  = (x & 2) ? s23 : s01;
    float inv = 1.0f / lf;

    #pragma unroll
    for (int dlt = 0; dlt < 4; dlt++) {
        uint lo = (uint)f2bf(oacc[dlt][0] * inv) | ((uint)f2bf(oacc[dlt][1] * inv) << 16);
        uint hi = (uint)f2bf(oacc[dlt][2] * inv) | ((uint)f2bf(oacc[dlt][3] * inv) << 16);
        *(uint2*)&gb[(btd + q_glob) * 512 + h * 64 + dlt * 16 + g * 4] = make_uint2(lo, hi);
    }
}

// ======================= launch =======================
extern "C" void kernel_launch(void* const* d_in, const int* in_sizes, int n_in,
                              void* d_out, int out_size, void* d_ws, size_t ws_size,
                              hipStream_t stream)
{
    const float* x    = (const float*)d_in[0];
    const float* cond = (const float*)d_in[1];
    const int*   tarr = (const int*)d_in[2];
    const float* lq_w = (const float*)d_in[3];
    const float* lq_b = (const float*)d_in[4];
    const float* lk_w = (const float*)d_in[5];
    const float* lk_b = (const float*)d_in[6];
    const float* lv_w = (const float*)d_in[7];
    const float* lv_b = (const float*)d_in[8];
    const float* lo_w = (const float*)d_in[9];
    const float* lo_b = (const float*)d_in[10];
    const float* gq_w = (const float*)d_in[11];
    const float* gq_b = (const float*)d_in[12];
    const float* gk_w = (const float*)d_in[13];
    const float* gk_b = (const float*)d_in[14];
    const float* gv_w = (const float*)d_in[15];
    const float* gv_b = (const float*)d_in[16];
    const float* go_w = (const float*)d_in[17];
    const float* go_b = (const float*)d_in[18];
    float* out = (float*)d_out;

    const size_t N = (size_t)BB * CC * TT;     // 4.19M elems
    char* w = (char*)d_ws;
    ushort* xtb  = (ushort*)w; w += N * 2;     // x^T  [b][t][c]
    ushort* ctb  = (ushort*)w; w += N * 2;     // cond^T
    ushort* buf1 = (ushort*)w; w += N * 2;     // lqt / gqt
    ushort* buf2 = (ushort*)w; w += N * 2;     // lkt / abT / gbuf
    ushort* buf3 = (ushort*)w; w += N * 2;     // lvt / gkt
    ushort* buf4 = (ushort*)w; w += N * 2;     // abuf / gvc
    ushort* wbf  = (ushort*)w; w += (size_t)8 * 512 * 512 * 2;
    float*  ctab = (float*)w;  w += (size_t)32 * 2048 * 4;
    float*  stab = (float*)w;

    dim3 blk(256);
    dim3 ggrid(64, 4);          // gemm: 64 n-tiles x 4 m-tiles
    dim3 tgrid(32, 8, BB);      // transpose: 32 t-tiles x 8 c-tiles

    rope_table_kernel<<<dim3(256), blk, 0, stream>>>(ctab, stab);
    wcvt_kernel<<<dim3(256, 8), blk, 0, stream>>>(lq_w, lk_w, lv_w, lo_w, gq_w, gk_w, gv_w, go_w, wbf);
    transpose_f32_kernel<<<tgrid, blk, 0, stream>>>(x,    xtb);
    transpose_f32_kernel<<<tgrid, blk, 0, stream>>>(cond, ctb);

    const size_t WN = 262144;

    // ---- local branch ----
    gemm_kernel<0><<<ggrid, blk, 0, stream>>>(wbf + 0 * WN, lq_b, xtb, buf1, nullptr, nullptr, nullptr, 1.f);
    gemm_kernel<0><<<ggrid, blk, 0, stream>>>(wbf + 1 * WN, lk_b, ctb, buf2, nullptr, nullptr, nullptr, 1.f);
    gemm_kernel<0><<<ggrid, blk, 0, stream>>>(wbf + 2 * WN, lv_b, ctb, buf3, nullptr, nullptr, nullptr, 1.f);
    local_attn_kernel<<<dim3(BB * HH * TT / 256), blk, 0, stream>>>(buf1, buf2, buf3, buf4);
    transpose_bf16_kernel<<<tgrid, blk, 0, stream>>>(buf4, buf2);   // abuf -> abT
    gemm_kernel<3><<<ggrid, blk, 0, stream>>>(wbf + 3 * WN, lo_b, buf2, out, nullptr, nullptr, tarr, 1.f);

    // ---- global branch ----
    gemm_kernel<1><<<ggrid, blk, 0, stream>>>(wbf + 4 * WN, gq_b, xtb, buf1, ctab, stab, nullptr, SCALE);
    gemm_kernel<1><<<ggrid, blk, 0, stream>>>(wbf + 5 * WN, gk_b, ctb, buf3, ctab, stab, nullptr, 1.0f);
    gemm_kernel<2><<<ggrid, blk, 0, stream>>>(wbf + 6 * WN, gv_b, ctb, buf4, nullptr, nullptr, nullptr, 1.f);
    flash_global_kernel<<<dim3(TT / 64, HH, BB), blk, 0, stream>>>(buf1, buf3, buf4, buf2);
    gemm_kernel<4><<<ggrid, blk, 0, stream>>>(wbf + 7 * WN, go_b, buf2, out, nullptr, nullptr, tarr, 1.f);
}

// Round 5
// 233.206 us; speedup vs baseline: 16.2054x; 1.3671x over previous
//
#include <hip/hip_runtime.h>
#include <math.h>

#define BB 4
#define CC 512
#define TT 2048
#define HH 8
#define DD 64

static constexpr float SCALE = 0.125f;   // D^-0.5, D=64

typedef __attribute__((ext_vector_type(8))) short  short8;
typedef __attribute__((ext_vector_type(4))) float  f32x4;

static __device__ __forceinline__ ushort f2bf(float f) {
    uint u = __float_as_uint(f);
    uint r = (u + 0x7fffu + ((u >> 16) & 1u)) >> 16;
    return (ushort)r;
}
static __device__ __forceinline__ float bf2f(ushort u) {
    return __uint_as_float((uint)u << 16);
}

typedef unsigned int u32;
typedef u32 __attribute__((address_space(1))) gu32;
typedef u32 __attribute__((address_space(3))) lu32;
static __device__ __forceinline__ void gload_lds16(const void* g, void* l) {
    __builtin_amdgcn_global_load_lds((const gu32*)g, (lu32*)l, 16, 0, 0);
}

// ======================= RoPE cos/sin table, [i][t] layout =======================
__global__ void rope_table_kernel(float* __restrict__ ctab, float* __restrict__ stab)
{
    int idx = blockIdx.x * blockDim.x + threadIdx.x;   // 32*2048 threads
    int i = idx >> 11;
    int t = idx & 2047;
    float ex   = (2.0f * (float)i) / 64.0f;
    float invf = powf(10000.0f, -ex);
    float ang  = (float)t * invf;
    ctab[idx] = cosf(ang);
    stab[idx] = sinf(ang);
}

// ======================= weight fp32 -> bf16 =======================
__global__ void wcvt_kernel(const float* w0, const float* w1, const float* w2, const float* w3,
                            const float* w4, const float* w5, const float* w6, const float* w7,
                            ushort* __restrict__ dst)
{
    const float* srcs[8] = {w0, w1, w2, w3, w4, w5, w6, w7};
    int wi = blockIdx.y;
    int idx = (blockIdx.x * 256 + threadIdx.x) * 4;
    float4 v = *(const float4*)&srcs[wi][idx];
    uint lo = (uint)f2bf(v.x) | ((uint)f2bf(v.y) << 16);
    uint hi = (uint)f2bf(v.z) | ((uint)f2bf(v.w) << 16);
    *(uint2*)&dst[(size_t)wi * 262144 + idx] = make_uint2(lo, hi);
}

// ======================= transpose [b][c][t] -> bf16 [b][t][c]  (x & cond fused) =======================
__global__ __launch_bounds__(256)
void transpose2_f32_kernel(const float* __restrict__ x, const float* __restrict__ cond,
                           ushort* __restrict__ xtb, ushort* __restrict__ ctb)
{
    __shared__ ushort L[64][66];
    const int z = blockIdx.z;                 // 0..7
    const float* in = (z < 4) ? x : cond;
    ushort* outp    = (z < 4) ? xtb : ctb;
    const int b = z & 3;
    const int t0 = blockIdx.x * 64, c0 = blockIdx.y * 64;
    const float* inb = in + (size_t)b * CC * TT;
    ushort* outb = outp + (size_t)b * TT * CC;
    const int lc = threadIdx.x >> 6;
    const int lt = threadIdx.x & 63;
    #pragma unroll
    for (int i = 0; i < 16; i++) {
        int c = i * 4 + lc;
        L[c][lt] = f2bf(inb[(size_t)(c0 + c) * TT + t0 + lt]);
    }
    __syncthreads();
    #pragma unroll
    for (int i = 0; i < 16; i++) {
        int t = i * 4 + lc;
        outb[(size_t)(t0 + t) * CC + c0 + lt] = L[lt][t];
    }
}

__global__ __launch_bounds__(256)
void transpose_bf16_kernel(const ushort* __restrict__ in, ushort* __restrict__ outp)
{
    __shared__ ushort L[64][66];
    const int t0 = blockIdx.x * 64, c0 = blockIdx.y * 64, b = blockIdx.z;
    const ushort* inb = in + (size_t)b * CC * TT;
    ushort* outb = outp + (size_t)b * TT * CC;
    const int lc = threadIdx.x >> 6;
    const int lt = threadIdx.x & 63;
    #pragma unroll
    for (int i = 0; i < 16; i++) {
        int c = i * 4 + lc;
        L[c][lt] = inb[(size_t)(c0 + c) * TT + t0 + lt];
    }
    __syncthreads();
    #pragma unroll
    for (int i = 0; i < 16; i++) {
        int t = i * 4 + lc;
        outb[(size_t)(t0 + t) * CC + c0 + lt] = L[lt][t];
    }
}

// ======================= MFMA GEMM core (shared macro-body) =======================
// C[m=512][n=8192(b*t)] = Wbf[m][k=512] . XT[n][k]; acc left in acc[4][4].
#define GEMM_BODY(Wp, XTp)                                                          \
    __shared__ __align__(16) ushort As[2][128][32];                                 \
    __shared__ __align__(16) ushort Bs[2][128][32];                                 \
    const int tid  = threadIdx.x;                                                   \
    const int wid  = tid >> 6;                                                      \
    const int lane = tid & 63;                                                      \
    const int x  = lane & 15;                                                       \
    const int gq = lane >> 4;                                                       \
    const int wm = wid >> 1, wn = wid & 1;                                          \
    const int m0 = blockIdx.y * 128;                                                \
    const int n0 = blockIdx.x * 128;                                                \
    const int srow = lane >> 2;                                                     \
    const int sblk = lane & 3;                                                      \
    f32x4 acc[4][4];                                                                \
    _Pragma("unroll")                                                               \
    for (int i = 0; i < 4; i++)                                                     \
        _Pragma("unroll")                                                           \
        for (int j = 0; j < 4; j++) acc[i][j] = (f32x4){0.f, 0.f, 0.f, 0.f};        \
    auto stage = [&](int bf, int k0) {                                              \
        _Pragma("unroll")                                                           \
        for (int c = 0; c < 2; c++) {                                               \
            int row = c * 64 + wid * 16 + srow;                                     \
            int db  = sblk ^ ((row >> 1) & 3);                                      \
            gload_lds16(&Wp[(size_t)(m0 + row) * 512 + k0 + db * 8],                \
                        &As[bf][c * 64 + wid * 16][0]);                             \
            gload_lds16(&XTp[(size_t)(n0 + row) * 512 + k0 + db * 8],               \
                        &Bs[bf][c * 64 + wid * 16][0]);                             \
        }                                                                           \
    };                                                                              \
    stage(0, 0);                                                                    \
    __syncthreads();                                                                \
    for (int ks = 0; ks < 16; ks++) {                                               \
        int cur = ks & 1;                                                           \
        if (ks < 15) stage(cur ^ 1, (ks + 1) * 32);                                 \
        short8 aF[4], bF[4];                                                        \
        _Pragma("unroll")                                                           \
        for (int mi = 0; mi < 4; mi++) {                                            \
            int row = wm * 64 + mi * 16 + x;                                        \
            aF[mi] = *(const short8*)&As[cur][row][(gq ^ ((row >> 1) & 3)) * 8];    \
        }                                                                           \
        _Pragma("unroll")                                                           \
        for (int nj = 0; nj < 4; nj++) {                                            \
            int row = wn * 64 + nj * 16 + x;                                        \
            bF[nj] = *(const short8*)&Bs[cur][row][(gq ^ ((row >> 1) & 3)) * 8];    \
        }                                                                           \
        _Pragma("unroll")                                                           \
        for (int mi = 0; mi < 4; mi++)                                              \
            _Pragma("unroll")                                                       \
            for (int nj = 0; nj < 4; nj++)                                          \
                acc[mi][nj] = __builtin_amdgcn_mfma_f32_16x16x32_bf16(aF[mi], bF[nj], acc[mi][nj], 0, 0, 0); \
        __syncthreads();                                                            \
    }

// ---- batched qkv GEMM: KIND 0 = local (3x bf16 C^T), KIND 1 = global (rope q, rope k, natural v)
template<int KIND>
__global__ __launch_bounds__(256)
void gemm3_kernel(const ushort* __restrict__ wbase,
                  const float* __restrict__ bias0, const float* __restrict__ bias1, const float* __restrict__ bias2,
                  const ushort* __restrict__ xt0, const ushort* __restrict__ xt1, const ushort* __restrict__ xt2,
                  ushort* __restrict__ y0, ushort* __restrict__ y1, ushort* __restrict__ y2,
                  const float* __restrict__ ctab, const float* __restrict__ stab)
{
    const int z = blockIdx.z;
    const ushort* Wp  = wbase + (size_t)z * 262144;
    const float* bias = (z == 0) ? bias0 : (z == 1) ? bias1 : bias2;
    const ushort* XTp = (z == 0) ? xt0 : (z == 1) ? xt1 : xt2;
    ushort* Y         = (z == 0) ? y0 : (z == 1) ? y1 : y2;
    const float qscale = (KIND == 1 && z == 0) ? SCALE : 1.0f;

    GEMM_BODY(Wp, XTp)

    const int bidx = (n0 + wn * 64) >> 11;
    #pragma unroll
    for (int mi = 0; mi < 4; mi++) {
        const int mb = m0 + wm * 64 + mi * 16 + 4 * gq;
        float bv[4];
        #pragma unroll
        for (int r = 0; r < 4; r++) bv[r] = bias[mb + r];
        #pragma unroll
        for (int nj = 0; nj < 4; nj++) {
            const int n  = n0 + wn * 64 + nj * 16 + x;
            const int tt = n & 2047;
            f32x4 v = acc[mi][nj];
            v[0] += bv[0]; v[1] += bv[1]; v[2] += bv[2]; v[3] += bv[3];
            if (KIND == 1 && z < 2) {
                const int i0 = (mb & 63) >> 1;
                float c0 = ctab[(size_t)i0 * 2048 + tt],       s0 = stab[(size_t)i0 * 2048 + tt];
                float c1 = ctab[(size_t)(i0 + 1) * 2048 + tt], s1 = stab[(size_t)(i0 + 1) * 2048 + tt];
                float e0 = (v[0] * c0 - v[1] * s0) * qscale;
                float e1 = (v[0] * s0 + v[1] * c0) * qscale;
                float e2 = (v[2] * c1 - v[3] * s1) * qscale;
                float e3 = (v[2] * s1 + v[3] * c1) * qscale;
                v[0] = e0; v[1] = e1; v[2] = e2; v[3] = e3;
            }
            if (KIND == 0 || z < 2) {      // bf16 C^T [b][t][c]
                uint lo = (uint)f2bf(v[0]) | ((uint)f2bf(v[1]) << 16);
                uint hi = (uint)f2bf(v[2]) | ((uint)f2bf(v[3]) << 16);
                *(uint2*)&Y[(size_t)n * 512 + mb] = make_uint2(lo, hi);
            } else {                        // bf16 natural [b][c][t]  (global v)
                #pragma unroll
                for (int r = 0; r < 4; r++)
                    Y[((size_t)bidx * 512 + mb + r) * 2048 + tt] = f2bf(v[r]);
            }
        }
    }
}

// ---- output-projection GEMM: MODE 3: d_out = sqrt(tn)*val; MODE 4: d_out += sqrt(1-tn)*val
template<int MODE>
__global__ __launch_bounds__(256)
void gemm_out_kernel(const ushort* __restrict__ Wp, const float* __restrict__ bias,
                     const ushort* __restrict__ XTp, float* __restrict__ Y,
                     const int* __restrict__ tarr)
{
    GEMM_BODY(Wp, XTp)

    const int bidx = (n0 + wn * 64) >> 11;
    float wl;
    if constexpr (MODE == 3) wl = sqrtf((float)tarr[bidx] / 999.0f);
    else                     wl = sqrtf(1.0f - (float)tarr[bidx] / 999.0f);

    #pragma unroll
    for (int mi = 0; mi < 4; mi++) {
        const int mb = m0 + wm * 64 + mi * 16 + 4 * gq;
        float bv[4];
        #pragma unroll
        for (int r = 0; r < 4; r++) bv[r] = bias[mb + r];
        #pragma unroll
        for (int nj = 0; nj < 4; nj++) {
            const int tt = (n0 + wn * 64 + nj * 16 + x) & 2047;
            f32x4 v = acc[mi][nj];
            #pragma unroll
            for (int r = 0; r < 4; r++) {
                size_t a = ((size_t)bidx * 512 + mb + r) * 2048 + tt;
                float val = v[r] + bv[r];
                if constexpr (MODE == 3) Y[a] = wl * val;
                else                     Y[a] = fmaf(wl, val, Y[a]);
            }
        }
    }
}

// ======================= local windowed attention (bf16 [t][c] in) =======================
__global__ __launch_bounds__(256)
void local_attn_kernel(const ushort* __restrict__ qt, const ushort* __restrict__ kt,
                       const ushort* __restrict__ vt, ushort* __restrict__ outb)
{
    int gidx = blockIdx.x * 256 + threadIdx.x;
    int t  = gidx & (TT - 1);
    int bh = gidx >> 11;
    int h  = bh & (HH - 1);
    int b  = bh >> 3;
    const size_t rb = (size_t)b * TT;
    const int co = h * DD;

    float qf[64];
    {
        const ushort* qp = qt + (rb + t) * 512 + co;
        #pragma unroll
        for (int i = 0; i < 8; i++) {
            short8 v = *(const short8*)&qp[i * 8];
            #pragma unroll
            for (int j = 0; j < 8; j++) qf[i * 8 + j] = bf2f((ushort)v[j]);
        }
    }

    int koff[16]; float msk[16];
    #pragma unroll
    for (int w = 0; w < 16; w++) {
        int kidx = t + w - 8;
        msk[w]  = (kidx >= 0 && kidx < TT) ? 1.0f : 0.0f;
        koff[w] = min(max(kidx, 0), TT - 1);
    }

    float dots[16];
    #pragma unroll
    for (int w = 0; w < 16; w++) {
        const ushort* kp = kt + (rb + koff[w]) * 512 + co;
        float d0 = 0.f, d1 = 0.f;
        #pragma unroll
        for (int i = 0; i < 8; i++) {
            short8 v = *(const short8*)&kp[i * 8];
            #pragma unroll
            for (int j = 0; j < 8; j += 2) {
                d0 = fmaf(qf[i * 8 + j],     bf2f((ushort)v[j]),     d0);
                d1 = fmaf(qf[i * 8 + j + 1], bf2f((ushort)v[j + 1]), d1);
            }
        }
        dots[w] = d0 + d1;
    }

    float m = -1e30f;
    #pragma unroll
    for (int w = 0; w < 16; w++) { dots[w] = dots[w] * SCALE * msk[w]; m = fmaxf(m, dots[w]); }
    float p[16], s = 0.f;
    #pragma unroll
    for (int w = 0; w < 16; w++) { p[w] = __expf(dots[w] - m); s += p[w]; }
    float inv = 1.0f / s;
    #pragma unroll
    for (int w = 0; w < 16; w++) p[w] *= msk[w] * inv;

    float oa[64];
    #pragma unroll
    for (int d = 0; d < 64; d++) oa[d] = 0.f;
    #pragma unroll
    for (int w = 0; w < 16; w++) {
        const ushort* vp = vt + (rb + koff[w]) * 512 + co;
        #pragma unroll
        for (int i = 0; i < 8; i++) {
            short8 v = *(const short8*)&vp[i * 8];
            #pragma unroll
            for (int j = 0; j < 8; j++)
                oa[i * 8 + j] = fmaf(p[w], bf2f((ushort)v[j]), oa[i * 8 + j]);
        }
    }

    // scrambled store (reference's (B,H,T,D)->(B,C,T) reshape), bf16 [c'][t']
    ushort* op = outb + ((size_t)b * CC + co + (t >> 5)) * TT + (size_t)(t & 31) * DD;
    #pragma unroll
    for (int i = 0; i < 16; i++) {
        uint lo = (uint)f2bf(oa[i * 4 + 0]) | ((uint)f2bf(oa[i * 4 + 1]) << 16);
        uint hi = (uint)f2bf(oa[i * 4 + 2]) | ((uint)f2bf(oa[i * 4 + 3]) << 16);
        *(uint2*)&op[i * 4] = make_uint2(lo, hi);
    }
}

// ======================= global flash attention (bf16 MFMA, swapped-S) =======================
// q,k: bf16 [b][t][c] (RoPE'd; q pre-scaled). v: bf16 [b][c][t]. out: bf16 [b][t][c].
// Per wave: 16 queries (q = lane&15 after swap). S^T = mfma(K_frag, Q_frag):
// lane x owns q, regs (tau,r) own k = 16*tau + 4*g + r. Softmax per-lane + 2 shfl.
// LDS maps (block-XOR swizzled; with 8-lane/phase b128 and 16-lane/phase b64
// processing all staged writes and fragment reads are conflict-free):
//   Ks byte(tk,d) = 128*tk + 16*((d>>3)^(tk&7)) + 2*(d&7)
//   Vs byte(d,t)  = 128*d  + 16*((t>>3)^(d&7))  + 2*(t&7)
//   Ps byte(row=wid*16+q, k) = 128*row + 16*((k>>3)^(q&7)) + 2*(k&7)   [wave-private rows!]
__global__ __launch_bounds__(256)
void flash_global_kernel(const ushort* __restrict__ qtd, const ushort* __restrict__ ktd,
                         const ushort* __restrict__ vb, ushort* __restrict__ gb)
{
    __shared__ __align__(16) ushort Ks[64 * 64];
    __shared__ __align__(16) ushort Vs[64 * 64];
    __shared__ __align__(16) ushort Ps[64 * 64];

    const int tid  = threadIdx.x;
    const int wid  = tid >> 6;
    const int lane = tid & 63;
    const int x    = lane & 15;
    const int g    = lane >> 4;

    const int q0 = blockIdx.x * 64;
    const int h  = blockIdx.y;
    const int b  = blockIdx.z;
    const size_t bh_ct = ((size_t)b * CC + h * DD) * TT;   // v [b][c][t]
    const size_t btd   = (size_t)b * TT;                   // [b][t][c] row base
    const ushort* vbh = vb + bh_ct;
    const int q_glob = q0 + wid * 16 + x;
    const int prow = wid * 16 + x;        // wave-private Ps row

    // ---- Q fragments (B-operand): lane supplies Q[q=x][d = kap*32 + g*8 + j] ----
    short8 aQ[2];
    {
        const ushort* qrow = qtd + (btd + q_glob) * 512 + h * 64;
        aQ[0] = *(const short8*)&qrow[g * 8];
        aQ[1] = *(const short8*)&qrow[32 + g * 8];
    }

    f32x4 oacc[4];
    #pragma unroll
    for (int d = 0; d < 4; d++) oacc[d] = (f32x4){0.f, 0.f, 0.f, 0.f};
    float m_run = -INFINITY, l_run = 0.0f;

    // staging indices
    const int ktk = tid >> 3;      // 0..31 (key row)
    const int kdb = tid & 7;       // 8-d block
    const int vd0 = tid >> 4;      // 0..15 (d row)
    const int vp2 = tid & 15;      // 4-t block

    short8 kreg[2];
    uint2  vreg[4];
    auto load_regs = [&](int kt0) {
        kreg[0] = *(const short8*)&ktd[(btd + kt0 + ktk) * 512 + h * 64 + kdb * 8];
        kreg[1] = *(const short8*)&ktd[(btd + kt0 + 32 + ktk) * 512 + h * 64 + kdb * 8];
        #pragma unroll
        for (int i = 0; i < 4; i++)
            vreg[i] = *(const uint2*)&vbh[(size_t)(vd0 + i * 16) * TT + kt0 + vp2 * 4];
    };

    load_regs(0);
    for (int kt = 0; kt < 32; kt++) {
        __syncthreads();
        // ---- LDS writes (b128 K, b64 V), conflict-free phases ----
        {
            int col = (kdb ^ (ktk & 7)) << 3;
            *(short8*)&Ks[ktk * 64 + col]        = kreg[0];
            *(short8*)&Ks[(ktk + 32) * 64 + col] = kreg[1];
        }
        #pragma unroll
        for (int i = 0; i < 4; i++) {
            int d = vd0 + i * 16;
            *(uint2*)&Vs[d * 64 + (((vp2 >> 1) ^ (d & 7)) << 3) + (vp2 & 1) * 4] = vreg[i];
        }
        __syncthreads();
        if (kt < 31) load_regs((kt + 1) * 64);   // T14: in flight across compute

        // ---- S^T = K Q^T : ST[tau][r] = S[k=16tau+4g+r][q=x] ----
        f32x4 ST[4];
        #pragma unroll
        for (int tau = 0; tau < 4; tau++) ST[tau] = (f32x4){0.f, 0.f, 0.f, 0.f};
        #pragma unroll
        for (int kap = 0; kap < 2; kap++)
            #pragma unroll
            for (int tau = 0; tau < 4; tau++) {
                short8 aK = *(const short8*)&Ks[(tau * 16 + x) * 64 + (((4 * kap + g) ^ (x & 7)) << 3)];
                ST[tau] = __builtin_amdgcn_mfma_f32_16x16x32_bf16(aK, aQ[kap], ST[tau], 0, 0, 0);
            }

        // ---- online softmax (q = x, per-lane scalars; reduce only across g) ----
        float mr = fmaxf(fmaxf(fmaxf(ST[0][0], ST[0][1]), fmaxf(ST[0][2], ST[0][3])),
                         fmaxf(fmaxf(ST[1][0], ST[1][1]), fmaxf(ST[1][2], ST[1][3])));
        mr = fmaxf(mr, fmaxf(fmaxf(fmaxf(ST[2][0], ST[2][1]), fmaxf(ST[2][2], ST[2][3])),
                             fmaxf(fmaxf(ST[3][0], ST[3][1]), fmaxf(ST[3][2], ST[3][3]))));
        mr = fmaxf(mr, __shfl_xor(mr, 16));
        mr = fmaxf(mr, __shfl_xor(mr, 32));

        float mnew = fmaxf(m_run, mr);
        float corr = __expf(m_run - mnew);
        m_run = mnew;

        float sm = 0.0f;
        #pragma unroll
        for (int tau = 0; tau < 4; tau++) {
            ST[tau][0] = __expf(ST[tau][0] - mnew);
            ST[tau][1] = __expf(ST[tau][1] - mnew);
            ST[tau][2] = __expf(ST[tau][2] - mnew);
            ST[tau][3] = __expf(ST[tau][3] - mnew);
            sm += (ST[tau][0] + ST[tau][1]) + (ST[tau][2] + ST[tau][3]);
        }
        sm += __shfl_xor(sm, 16);
        sm += __shfl_xor(sm, 32);
        l_run = l_run * corr + sm;

        // ---- rescale out-acc (per-lane corr, no shuffles) ----
        #pragma unroll
        for (int d = 0; d < 4; d++) {
            oacc[d][0] *= corr; oacc[d][1] *= corr;
            oacc[d][2] *= corr; oacc[d][3] *= corr;
        }

        // ---- P -> Ps via cvt_pk (4x uint2 writes into wave-private row) ----
        #pragma unroll
        for (int tau = 0; tau < 4; tau++) {
            uint lo, hi;
            asm("v_cvt_pk_bf16_f32 %0, %1, %2" : "=v"(lo) : "v"(ST[tau][0]), "v"(ST[tau][1]));
            asm("v_cvt_pk_bf16_f32 %0, %1, %2" : "=v"(hi) : "v"(ST[tau][2]), "v"(ST[tau][3]));
            int kblk = 2 * tau + (g >> 1);
            *(uint2*)&Ps[prow * 64 + ((kblk ^ (x & 7)) << 3) + (g & 1) * 4] = make_uint2(lo, hi);
        }

        // ---- PV: out^T += V^T P^T  (bP = b128 reads of own-q wave-private row) ----
        short8 bP[2];
        bP[0] = *(const short8*)&Ps[prow * 64 + (((g    ) ^ (x & 7)) << 3)];
        bP[1] = *(const short8*)&Ps[prow * 64 + (((4 + g) ^ (x & 7)) << 3)];
        #pragma unroll
        for (int dlt = 0; dlt < 4; dlt++)
            #pragma unroll
            for (int kap = 0; kap < 2; kap++) {
                short8 aV = *(const short8*)&Vs[(dlt * 16 + x) * 64 + (((4 * kap + g) ^ (x & 7)) << 3)];
                oacc[dlt] = __builtin_amdgcn_mfma_f32_16x16x32_bf16(aV, bP[kap], oacc[dlt], 0, 0, 0);
            }
    }

    // ---- final normalize (per-lane) + store bf16 [b][t][c] ----
    float inv = 1.0f / l_run;
    #pragma unroll
    for (int dlt = 0; dlt < 4; dlt++) {
        uint lo = (uint)f2bf(oacc[dlt][0] * inv) | ((uint)f2bf(oacc[dlt][1] * inv) << 16);
        uint hi = (uint)f2bf(oacc[dlt][2] * inv) | ((uint)f2bf(oacc[dlt][3] * inv) << 16);
        *(uint2*)&gb[(btd + q_glob) * 512 + h * 64 + dlt * 16 + g * 4] = make_uint2(lo, hi);
    }
}

// ======================= launch =======================
extern "C" void kernel_launch(void* const* d_in, const int* in_sizes, int n_in,
                              void* d_out, int out_size, void* d_ws, size_t ws_size,
                              hipStream_t stream)
{
    const float* x    = (const float*)d_in[0];
    const float* cond = (const float*)d_in[1];
    const int*   tarr = (const int*)d_in[2];
    const float* lq_w = (const float*)d_in[3];
    const float* lq_b = (const float*)d_in[4];
    const float* lk_w = (const float*)d_in[5];
    const float* lk_b = (const float*)d_in[6];
    const float* lv_w = (const float*)d_in[7];
    const float* lv_b = (const float*)d_in[8];
    const float* lo_w = (const float*)d_in[9];
    const float* lo_b = (const float*)d_in[10];
    const float* gq_w = (const float*)d_in[11];
    const float* gq_b = (const float*)d_in[12];
    const float* gk_w = (const float*)d_in[13];
    const float* gk_b = (const float*)d_in[14];
    const float* gv_w = (const float*)d_in[15];
    const float* gv_b = (const float*)d_in[16];
    const float* go_w = (const float*)d_in[17];
    const float* go_b = (const float*)d_in[18];
    float* out = (float*)d_out;

    const size_t N = (size_t)BB * CC * TT;
    char* w = (char*)d_ws;
    ushort* xtb  = (ushort*)w; w += N * 2;     // x^T  [b][t][c]
    ushort* ctb  = (ushort*)w; w += N * 2;     // cond^T
    ushort* buf1 = (ushort*)w; w += N * 2;     // lqt / gqt
    ushort* buf2 = (ushort*)w; w += N * 2;     // lkt / abT / gbuf
    ushort* buf3 = (ushort*)w; w += N * 2;     // lvt / gkt
    ushort* buf4 = (ushort*)w; w += N * 2;     // abuf / gvc
    ushort* wbf  = (ushort*)w; w += (size_t)8 * 512 * 512 * 2;
    float*  ctab = (float*)w;  w += (size_t)32 * 2048 * 4;
    float*  stab = (float*)w;

    dim3 blk(256);
    dim3 g3grid(64, 4, 3);
    dim3 ogrid(64, 4);
    dim3 t2grid(32, 8, 8);
    dim3 tgrid(32, 8, BB);

    const size_t WN = 262144;

    rope_table_kernel<<<dim3(256), blk, 0, stream>>>(ctab, stab);
    wcvt_kernel<<<dim3(256, 8), blk, 0, stream>>>(lq_w, lk_w, lv_w, lo_w, gq_w, gk_w, gv_w, go_w, wbf);
    transpose2_f32_kernel<<<t2grid, blk, 0, stream>>>(x, cond, xtb, ctb);

    // ---- local branch ----
    gemm3_kernel<0><<<g3grid, blk, 0, stream>>>(wbf, lq_b, lk_b, lv_b,
                                                xtb, ctb, ctb, buf1, buf2, buf3, nullptr, nullptr);
    local_attn_kernel<<<dim3(BB * HH * TT / 256), blk, 0, stream>>>(buf1, buf2, buf3, buf4);
    transpose_bf16_kernel<<<tgrid, blk, 0, stream>>>(buf4, buf2);   // abuf -> abT
    gemm_out_kernel<3><<<ogrid, blk, 0, stream>>>(wbf + 3 * WN, lo_b, buf2, out, tarr);

    // ---- global branch ----
    gemm3_kernel<1><<<g3grid, blk, 0, stream>>>(wbf + 4 * WN, gq_b, gk_b, gv_b,
                                                xtb, ctb, ctb, buf1, buf3, buf4, ctab, stab);
    flash_global_kernel<<<dim3(TT / 64, HH, BB), blk, 0, stream>>>(buf1, buf3, buf4, buf2);
    gemm_out_kernel<4><<<ogrid, blk, 0, stream>>>(wbf + 7 * WN, go_b, buf2, out, tarr);
}

// Round 6
// 206.428 us; speedup vs baseline: 18.3076x; 1.1297x over previous
//
#include <hip/hip_runtime.h>
#include <math.h>

#define BB 4
#define CC 512
#define TT 2048
#define HH 8
#define DD 64

static constexpr float SCALE = 0.125f;                 // D^-0.5
static constexpr float QK_SCALE_LOG2 = 0.125f * 1.4426950408889634f;  // fold log2(e): softmax in exp2 domain

typedef __attribute__((ext_vector_type(8))) short  short8;
typedef __attribute__((ext_vector_type(4))) float  f32x4;

static __device__ __forceinline__ ushort f2bf(float f) {
    uint u = __float_as_uint(f);
    uint r = (u + 0x7fffu + ((u >> 16) & 1u)) >> 16;
    return (ushort)r;
}
static __device__ __forceinline__ float bf2f(ushort u) {
    return __uint_as_float((uint)u << 16);
}

typedef unsigned int u32;
typedef u32 __attribute__((address_space(1))) gu32;
typedef u32 __attribute__((address_space(3))) lu32;
static __device__ __forceinline__ void gload_lds16(const void* g, void* l) {
    __builtin_amdgcn_global_load_lds((const gu32*)g, (lu32*)l, 16, 0, 0);
}

// ======================= RoPE cos/sin table, [i][t] layout =======================
__global__ void rope_table_kernel(float* __restrict__ ctab, float* __restrict__ stab)
{
    int idx = blockIdx.x * blockDim.x + threadIdx.x;   // 32*2048 threads
    int i = idx >> 11;
    int t = idx & 2047;
    float ex   = (2.0f * (float)i) / 64.0f;
    float invf = powf(10000.0f, -ex);
    float ang  = (float)t * invf;
    ctab[idx] = cosf(ang);
    stab[idx] = sinf(ang);
}

// ======================= weight fp32 -> bf16 =======================
// wi 0..5 -> wbf (qkv weights, 512x512 each); wi 6,7 -> wc combined [o][1024] halves
__global__ void wcvt_kernel(const float* w0, const float* w1, const float* w2, const float* w3,
                            const float* w4, const float* w5, const float* w6, const float* w7,
                            ushort* __restrict__ wbf, ushort* __restrict__ wc)
{
    const float* srcs[8] = {w0, w1, w2, w3, w4, w5, w6, w7};
    int wi = blockIdx.y;
    int idx = (blockIdx.x * 256 + threadIdx.x) * 4;
    float4 v = *(const float4*)&srcs[wi][idx];
    uint lo = (uint)f2bf(v.x) | ((uint)f2bf(v.y) << 16);
    uint hi = (uint)f2bf(v.z) | ((uint)f2bf(v.w) << 16);
    uint2 pk = make_uint2(lo, hi);
    if (wi < 6) {
        *(uint2*)&wbf[(size_t)wi * 262144 + idx] = pk;
    } else {
        int row = idx >> 9, col = idx & 511;
        *(uint2*)&wc[(size_t)row * 1024 + (wi - 6) * 512 + col] = pk;
    }
}

// ======================= transpose [b][c][t] -> bf16 [b][t][c]  (x & cond fused) =======================
__global__ __launch_bounds__(256)
void transpose2_f32_kernel(const float* __restrict__ x, const float* __restrict__ cond,
                           ushort* __restrict__ xtb, ushort* __restrict__ ctb)
{
    __shared__ ushort L[64][66];
    const int z = blockIdx.z;                 // 0..7
    const float* in = (z < 4) ? x : cond;
    ushort* outp    = (z < 4) ? xtb : ctb;
    const int b = z & 3;
    const int t0 = blockIdx.x * 64, c0 = blockIdx.y * 64;
    const float* inb = in + (size_t)b * CC * TT;
    ushort* outb = outp + (size_t)b * TT * CC;
    const int lc = threadIdx.x >> 6;
    const int lt = threadIdx.x & 63;
    #pragma unroll
    for (int i = 0; i < 16; i++) {
        int c = i * 4 + lc;
        L[c][lt] = f2bf(inb[(size_t)(c0 + c) * TT + t0 + lt]);
    }
    __syncthreads();
    #pragma unroll
    for (int i = 0; i < 16; i++) {
        int t = i * 4 + lc;
        outb[(size_t)(t0 + t) * CC + c0 + lt] = L[lt][t];
    }
}

// ---- scrambled local-attn output [b][c][t] -> AG[b][t][0..512) (row stride 1024) ----
__global__ __launch_bounds__(256)
void transpose_bf16_kernel(const ushort* __restrict__ in, ushort* __restrict__ AG)
{
    __shared__ ushort L[64][66];
    const int t0 = blockIdx.x * 64, c0 = blockIdx.y * 64, b = blockIdx.z;
    const ushort* inb = in + (size_t)b * CC * TT;
    ushort* outb = AG + (size_t)b * TT * 1024;
    const int lc = threadIdx.x >> 6;
    const int lt = threadIdx.x & 63;
    #pragma unroll
    for (int i = 0; i < 16; i++) {
        int c = i * 4 + lc;
        L[c][lt] = inb[(size_t)(c0 + c) * TT + t0 + lt];
    }
    __syncthreads();
    #pragma unroll
    for (int i = 0; i < 16; i++) {
        int t = i * 4 + lc;
        outb[(size_t)(t0 + t) * 1024 + c0 + lt] = L[lt][t];
    }
}

// ======================= MFMA GEMM core (shared macro-body, K-dim param) =======================
// C[m=512][n=8192(b*t)] = Wp[m][KD] . XTp[n][KD]; acc left in acc[4][4].
#define GEMM_BODY(Wp, XTp, KD)                                                      \
    __shared__ __align__(16) ushort As[2][128][32];                                 \
    __shared__ __align__(16) ushort Bs[2][128][32];                                 \
    const int tid  = threadIdx.x;                                                   \
    const int wid  = tid >> 6;                                                      \
    const int lane = tid & 63;                                                      \
    const int x  = lane & 15;                                                       \
    const int gq = lane >> 4;                                                       \
    const int wm = wid >> 1, wn = wid & 1;                                          \
    const int m0 = blockIdx.y * 128;                                                \
    const int n0 = blockIdx.x * 128;                                                \
    const int srow = lane >> 2;                                                     \
    const int sblk = lane & 3;                                                      \
    f32x4 acc[4][4];                                                                \
    _Pragma("unroll")                                                               \
    for (int i = 0; i < 4; i++)                                                     \
        _Pragma("unroll")                                                           \
        for (int j = 0; j < 4; j++) acc[i][j] = (f32x4){0.f, 0.f, 0.f, 0.f};        \
    auto stage = [&](int bf, int k0) {                                              \
        _Pragma("unroll")                                                           \
        for (int c = 0; c < 2; c++) {                                               \
            int row = c * 64 + wid * 16 + srow;                                     \
            int db  = sblk ^ ((row >> 1) & 3);                                      \
            gload_lds16(&Wp[(size_t)(m0 + row) * KD + k0 + db * 8],                 \
                        &As[bf][c * 64 + wid * 16][0]);                             \
            gload_lds16(&XTp[(size_t)(n0 + row) * KD + k0 + db * 8],                \
                        &Bs[bf][c * 64 + wid * 16][0]);                             \
        }                                                                           \
    };                                                                              \
    stage(0, 0);                                                                    \
    __syncthreads();                                                                \
    for (int ks = 0; ks < (KD) / 32; ks++) {                                        \
        int cur = ks & 1;                                                           \
        if (ks < (KD) / 32 - 1) stage(cur ^ 1, (ks + 1) * 32);                      \
        short8 aF[4], bF[4];                                                        \
        _Pragma("unroll")                                                           \
        for (int mi = 0; mi < 4; mi++) {                                            \
            int row = wm * 64 + mi * 16 + x;                                        \
            aF[mi] = *(const short8*)&As[cur][row][(gq ^ ((row >> 1) & 3)) * 8];    \
        }                                                                           \
        _Pragma("unroll")                                                           \
        for (int nj = 0; nj < 4; nj++) {                                            \
            int row = wn * 64 + nj * 16 + x;                                        \
            bF[nj] = *(const short8*)&Bs[cur][row][(gq ^ ((row >> 1) & 3)) * 8];    \
        }                                                                           \
        _Pragma("unroll")                                                           \
        for (int mi = 0; mi < 4; mi++)                                              \
            _Pragma("unroll")                                                       \
            for (int nj = 0; nj < 4; nj++)                                          \
                acc[mi][nj] = __builtin_amdgcn_mfma_f32_16x16x32_bf16(aF[mi], bF[nj], acc[mi][nj], 0, 0, 0); \
        __syncthreads();                                                            \
    }

// ---- all 6 qkv projections in one dispatch ----
// z0:lq z1:lk z2:lv (bf16 C^T) | z3:gq (C^T, rope, qscale) z4:gk (C^T, rope) z5:gv (natural)
__global__ __launch_bounds__(256)
void gemm6_kernel(const ushort* __restrict__ wbase,
                  const float* __restrict__ b0, const float* __restrict__ b1, const float* __restrict__ b2,
                  const float* __restrict__ b3, const float* __restrict__ b4, const float* __restrict__ b5,
                  const ushort* __restrict__ xtb, const ushort* __restrict__ ctb,
                  ushort* __restrict__ y0, ushort* __restrict__ y1, ushort* __restrict__ y2,
                  ushort* __restrict__ y3, ushort* __restrict__ y4, ushort* __restrict__ y5,
                  const float* __restrict__ ctab, const float* __restrict__ stab)
{
    const int z = blockIdx.z;
    const ushort* Wp  = wbase + (size_t)z * 262144;
    const float* bias = (z == 0) ? b0 : (z == 1) ? b1 : (z == 2) ? b2 : (z == 3) ? b3 : (z == 4) ? b4 : b5;
    const ushort* XTp = (z == 0 || z == 3) ? xtb : ctb;
    ushort* Y = (z == 0) ? y0 : (z == 1) ? y1 : (z == 2) ? y2 : (z == 3) ? y3 : (z == 4) ? y4 : y5;
    const bool do_rope = (z == 3 || z == 4);
    const float qscale = (z == 3) ? QK_SCALE_LOG2 : 1.0f;

    GEMM_BODY(Wp, XTp, 512)

    const int bidx = (n0 + wn * 64) >> 11;
    #pragma unroll
    for (int mi = 0; mi < 4; mi++) {
        const int mb = m0 + wm * 64 + mi * 16 + 4 * gq;
        float bv[4];
        #pragma unroll
        for (int r = 0; r < 4; r++) bv[r] = bias[mb + r];
        #pragma unroll
        for (int nj = 0; nj < 4; nj++) {
            const int n  = n0 + wn * 64 + nj * 16 + x;
            const int tt = n & 2047;
            f32x4 v = acc[mi][nj];
            v[0] += bv[0]; v[1] += bv[1]; v[2] += bv[2]; v[3] += bv[3];
            if (do_rope) {
                const int i0 = (mb & 63) >> 1;
                float c0 = ctab[(size_t)i0 * 2048 + tt],       s0 = stab[(size_t)i0 * 2048 + tt];
                float c1 = ctab[(size_t)(i0 + 1) * 2048 + tt], s1 = stab[(size_t)(i0 + 1) * 2048 + tt];
                float e0 = (v[0] * c0 - v[1] * s0) * qscale;
                float e1 = (v[0] * s0 + v[1] * c0) * qscale;
                float e2 = (v[2] * c1 - v[3] * s1) * qscale;
                float e3 = (v[2] * s1 + v[3] * c1) * qscale;
                v[0] = e0; v[1] = e1; v[2] = e2; v[3] = e3;
            }
            if (z != 5) {      // bf16 C^T [b][t][c]
                uint lo = (uint)f2bf(v[0]) | ((uint)f2bf(v[1]) << 16);
                uint hi = (uint)f2bf(v[2]) | ((uint)f2bf(v[3]) << 16);
                *(uint2*)&Y[(size_t)n * 512 + mb] = make_uint2(lo, hi);
            } else {           // bf16 natural [b][c][t]  (global v)
                #pragma unroll
                for (int r = 0; r < 4; r++)
                    Y[((size_t)bidx * 512 + mb + r) * 2048 + tt] = f2bf(v[r]);
            }
        }
    }
}

// ---- combined output projection: d_out = Wc[512][1024] . AG[n][1024] + (sl*bl + sg*bg) ----
// AG rows already hold [sl*a | sg*g]; bias mixed per batch in epilogue. Single fp32 write.
__global__ __launch_bounds__(256)
void gemm_comb_kernel(const ushort* __restrict__ Wp,
                      const float* __restrict__ bl, const float* __restrict__ bg,
                      const ushort* __restrict__ XTp, float* __restrict__ Y,
                      const int* __restrict__ tarr)
{
    GEMM_BODY(Wp, XTp, 1024)

    const int bidx = (n0 + wn * 64) >> 11;
    float tn = (float)tarr[bidx] / 999.0f;
    float sl = sqrtf(tn), sg = sqrtf(1.0f - tn);

    #pragma unroll
    for (int mi = 0; mi < 4; mi++) {
        const int mb = m0 + wm * 64 + mi * 16 + 4 * gq;
        float bv[4];
        #pragma unroll
        for (int r = 0; r < 4; r++) bv[r] = sl * bl[mb + r] + sg * bg[mb + r];
        #pragma unroll
        for (int nj = 0; nj < 4; nj++) {
            const int tt = (n0 + wn * 64 + nj * 16 + x) & 2047;
            f32x4 v = acc[mi][nj];
            #pragma unroll
            for (int r = 0; r < 4; r++)
                Y[((size_t)bidx * 512 + mb + r) * 2048 + tt] = v[r] + bv[r];
        }
    }
}

// ======================= local windowed attention (bf16 [t][c] in, sl-scaled out) =======================
__global__ __launch_bounds__(256)
void local_attn_kernel(const ushort* __restrict__ qt, const ushort* __restrict__ kt,
                       const ushort* __restrict__ vt, ushort* __restrict__ outb,
                       const int* __restrict__ tarr)
{
    int gidx = blockIdx.x * 256 + threadIdx.x;
    int t  = gidx & (TT - 1);
    int bh = gidx >> 11;
    int h  = bh & (HH - 1);
    int b  = bh >> 3;
    const size_t rb = (size_t)b * TT;
    const int co = h * DD;
    const float wl = sqrtf((float)tarr[b] / 999.0f);

    float qf[64];
    {
        const ushort* qp = qt + (rb + t) * 512 + co;
        #pragma unroll
        for (int i = 0; i < 8; i++) {
            short8 v = *(const short8*)&qp[i * 8];
            #pragma unroll
            for (int j = 0; j < 8; j++) qf[i * 8 + j] = bf2f((ushort)v[j]);
        }
    }

    int koff[16]; float msk[16];
    #pragma unroll
    for (int w = 0; w < 16; w++) {
        int kidx = t + w - 8;
        msk[w]  = (kidx >= 0 && kidx < TT) ? 1.0f : 0.0f;
        koff[w] = min(max(kidx, 0), TT - 1);
    }

    float dots[16];
    #pragma unroll
    for (int w = 0; w < 16; w++) {
        const ushort* kp = kt + (rb + koff[w]) * 512 + co;
        float d0 = 0.f, d1 = 0.f;
        #pragma unroll
        for (int i = 0; i < 8; i++) {
            short8 v = *(const short8*)&kp[i * 8];
            #pragma unroll
            for (int j = 0; j < 8; j += 2) {
                d0 = fmaf(qf[i * 8 + j],     bf2f((ushort)v[j]),     d0);
                d1 = fmaf(qf[i * 8 + j + 1], bf2f((ushort)v[j + 1]), d1);
            }
        }
        dots[w] = d0 + d1;
    }

    float m = -1e30f;
    #pragma unroll
    for (int w = 0; w < 16; w++) { dots[w] = dots[w] * SCALE * msk[w]; m = fmaxf(m, dots[w]); }
    float p[16], s = 0.f;
    #pragma unroll
    for (int w = 0; w < 16; w++) { p[w] = __expf(dots[w] - m); s += p[w]; }
    float inv = wl / s;                       // fold the mix weight into the normalize
    #pragma unroll
    for (int w = 0; w < 16; w++) p[w] *= msk[w] * inv;

    float oa[64];
    #pragma unroll
    for (int d = 0; d < 64; d++) oa[d] = 0.f;
    #pragma unroll
    for (int w = 0; w < 16; w++) {
        const ushort* vp = vt + (rb + koff[w]) * 512 + co;
        #pragma unroll
        for (int i = 0; i < 8; i++) {
            short8 v = *(const short8*)&vp[i * 8];
            #pragma unroll
            for (int j = 0; j < 8; j++)
                oa[i * 8 + j] = fmaf(p[w], bf2f((ushort)v[j]), oa[i * 8 + j]);
        }
    }

    // scrambled store (reference's (B,H,T,D)->(B,C,T) reshape), bf16 [c'][t']
    ushort* op = outb + ((size_t)b * CC + co + (t >> 5)) * TT + (size_t)(t & 31) * DD;
    #pragma unroll
    for (int i = 0; i < 16; i++) {
        uint lo = (uint)f2bf(oa[i * 4 + 0]) | ((uint)f2bf(oa[i * 4 + 1]) << 16);
        uint hi = (uint)f2bf(oa[i * 4 + 2]) | ((uint)f2bf(oa[i * 4 + 3]) << 16);
        *(uint2*)&op[i * 4] = make_uint2(lo, hi);
    }
}

// ======================= global flash attention (bf16 MFMA, swapped-S, exp2 domain) =======================
// q: [b][t][c] pre-scaled by SCALE*log2e + RoPE'd; k: [b][t][c] RoPE'd; v: [b][c][t].
// out: AG[b][t][512..1024) scaled by sg (row stride 1024).
// LDS maps (block-XOR swizzled, conflict-free under 8/16-lane phases):
//   Ks byte(tk,d) = 128*tk + 16*((d>>3)^(tk&7)) + 2*(d&7)
//   Vs byte(d,t)  = 128*d  + 16*((t>>3)^(d&7))  + 2*(t&7)
//   Ps byte(row=wid*16+q, k) = 128*row + 16*((k>>3)^(q&7)) + 2*(k&7)   [wave-private rows]
__global__ __launch_bounds__(256)
void flash_global_kernel(const ushort* __restrict__ qtd, const ushort* __restrict__ ktd,
                         const ushort* __restrict__ vb, ushort* __restrict__ AG,
                         const int* __restrict__ tarr)
{
    __shared__ __align__(16) ushort Ks[64 * 64];
    __shared__ __align__(16) ushort Vs[64 * 64];
    __shared__ __align__(16) ushort Ps[64 * 64];

    const int tid  = threadIdx.x;
    const int wid  = tid >> 6;
    const int lane = tid & 63;
    const int x    = lane & 15;
    const int g    = lane >> 4;

    const int q0 = blockIdx.x * 64;
    const int h  = blockIdx.y;
    const int b  = blockIdx.z;
    const size_t bh_ct = ((size_t)b * CC + h * DD) * TT;   // v [b][c][t]
    const size_t btd   = (size_t)b * TT;                   // [b][t][c] row base
    const int q_glob = q0 + wid * 16 + x;
    const int prow = wid * 16 + x;        // wave-private Ps row
    const float sg_mix = sqrtf(1.0f - (float)tarr[b] / 999.0f);

    // ---- Q fragments (B-operand): lane supplies Q[q=x][d = kap*32 + g*8 + j] ----
    short8 aQ[2];
    {
        const ushort* qrow = qtd + (btd + q_glob) * 512 + h * 64;
        aQ[0] = *(const short8*)&qrow[g * 8];
        aQ[1] = *(const short8*)&qrow[32 + g * 8];
    }

    f32x4 oacc[4];
    #pragma unroll
    for (int d = 0; d < 4; d++) oacc[d] = (f32x4){0.f, 0.f, 0.f, 0.f};
    float m_run = -INFINITY, l_run = 0.0f;

    // staging indices + hoisted pointers (advance by constant per tile)
    const int ktk = tid >> 3;      // 0..31 (key row)
    const int kdb = tid & 7;       // 8-d block
    const int vd0 = tid >> 4;      // 0..15 (d row)
    const int vp2 = tid & 15;      // 4-t block
    const ushort* kp = ktd + (btd + ktk) * 512 + h * 64 + kdb * 8;
    const ushort* vp = vb + bh_ct + (size_t)vd0 * TT + vp2 * 4;

    short8 kreg[2];
    uint2  vreg[4];
    // prologue loads (tile 0)
    kreg[0] = *(const short8*)kp;
    kreg[1] = *(const short8*)(kp + 32 * 512);
    #pragma unroll
    for (int i = 0; i < 4; i++) vreg[i] = *(const uint2*)(vp + (size_t)i * 16 * TT);
    kp += 64 * 512; vp += 64;

    for (int kt = 0; kt < 32; kt++) {
        __syncthreads();
        // ---- LDS writes (b128 K, b64 V), conflict-free phases ----
        {
            int col = (kdb ^ (ktk & 7)) << 3;
            *(short8*)&Ks[ktk * 64 + col]        = kreg[0];
            *(short8*)&Ks[(ktk + 32) * 64 + col] = kreg[1];
        }
        #pragma unroll
        for (int i = 0; i < 4; i++) {
            int d = vd0 + i * 16;
            *(uint2*)&Vs[d * 64 + (((vp2 >> 1) ^ (d & 7)) << 3) + (vp2 & 1) * 4] = vreg[i];
        }
        __syncthreads();
        if (kt < 31) {   // T14: next-tile loads in flight across compute
            kreg[0] = *(const short8*)kp;
            kreg[1] = *(const short8*)(kp + 32 * 512);
            #pragma unroll
            for (int i = 0; i < 4; i++) vreg[i] = *(const uint2*)(vp + (size_t)i * 16 * TT);
            kp += 64 * 512; vp += 64;
        }

        // ---- S^T = K Q^T : ST[tau][r] = S[k=16tau+4g+r][q=x]  (log2 units) ----
        f32x4 ST[4];
        #pragma unroll
        for (int tau = 0; tau < 4; tau++) ST[tau] = (f32x4){0.f, 0.f, 0.f, 0.f};
        __builtin_amdgcn_s_setprio(1);
        #pragma unroll
        for (int kap = 0; kap < 2; kap++)
            #pragma unroll
            for (int tau = 0; tau < 4; tau++) {
                short8 aK = *(const short8*)&Ks[(tau * 16 + x) * 64 + (((4 * kap + g) ^ (x & 7)) << 3)];
                ST[tau] = __builtin_amdgcn_mfma_f32_16x16x32_bf16(aK, aQ[kap], ST[tau], 0, 0, 0);
            }
        __builtin_amdgcn_s_setprio(0);

        // ---- online softmax (q = x per-lane; reduce across g only) ----
        float mr = fmaxf(fmaxf(fmaxf(ST[0][0], ST[0][1]), fmaxf(ST[0][2], ST[0][3])),
                         fmaxf(fmaxf(ST[1][0], ST[1][1]), fmaxf(ST[1][2], ST[1][3])));
        mr = fmaxf(mr, fmaxf(fmaxf(fmaxf(ST[2][0], ST[2][1]), fmaxf(ST[2][2], ST[2][3])),
                             fmaxf(fmaxf(ST[3][0], ST[3][1]), fmaxf(ST[3][2], ST[3][3]))));
        mr = fmaxf(mr, __shfl_xor(mr, 16));
        mr = fmaxf(mr, __shfl_xor(mr, 32));

        // T13 defer-rescale: only rescale when some query's max grew by > 8 (log2 units)
        if (__any(mr > m_run + 8.0f)) {
            float mnew = fmaxf(m_run, mr);
            float corr = __builtin_amdgcn_exp2f(m_run - mnew);
            m_run = mnew;
            l_run *= corr;
            #pragma unroll
            for (int d = 0; d < 4; d++) {
                oacc[d][0] *= corr; oacc[d][1] *= corr;
                oacc[d][2] *= corr; oacc[d][3] *= corr;
            }
        }

        float sm = 0.0f;
        #pragma unroll
        for (int tau = 0; tau < 4; tau++) {
            ST[tau][0] = __builtin_amdgcn_exp2f(ST[tau][0] - m_run);
            ST[tau][1] = __builtin_amdgcn_exp2f(ST[tau][1] - m_run);
            ST[tau][2] = __builtin_amdgcn_exp2f(ST[tau][2] - m_run);
            ST[tau][3] = __builtin_amdgcn_exp2f(ST[tau][3] - m_run);
            sm += (ST[tau][0] + ST[tau][1]) + (ST[tau][2] + ST[tau][3]);
        }
        sm += __shfl_xor(sm, 16);
        sm += __shfl_xor(sm, 32);
        l_run += sm;

        // ---- P -> Ps via cvt_pk (4x uint2 writes into wave-private row) ----
        #pragma unroll
        for (int tau = 0; tau < 4; tau++) {
            uint lo, hi;
            asm("v_cvt_pk_bf16_f32 %0, %1, %2" : "=v"(lo) : "v"(ST[tau][0]), "v"(ST[tau][1]));
            asm("v_cvt_pk_bf16_f32 %0, %1, %2" : "=v"(hi) : "v"(ST[tau][2]), "v"(ST[tau][3]));
            int kblk = 2 * tau + (g >> 1);
            *(uint2*)&Ps[prow * 64 + ((kblk ^ (x & 7)) << 3) + (g & 1) * 4] = make_uint2(lo, hi);
        }

        // ---- PV: out^T += V^T P^T  (bP = b128 reads of own-q wave-private row) ----
        short8 bP[2];
        bP[0] = *(const short8*)&Ps[prow * 64 + (((g    ) ^ (x & 7)) << 3)];
        bP[1] = *(const short8*)&Ps[prow * 64 + (((4 + g) ^ (x & 7)) << 3)];
        __builtin_amdgcn_s_setprio(1);
        #pragma unroll
        for (int dlt = 0; dlt < 4; dlt++)
            #pragma unroll
            for (int kap = 0; kap < 2; kap++) {
                short8 aV = *(const short8*)&Vs[(dlt * 16 + x) * 64 + (((4 * kap + g) ^ (x & 7)) << 3)];
                oacc[dlt] = __builtin_amdgcn_mfma_f32_16x16x32_bf16(aV, bP[kap], oacc[dlt], 0, 0, 0);
            }
        __builtin_amdgcn_s_setprio(0);
    }

    // ---- final normalize (per-lane, sg mix folded) + store bf16 AG[b][t][512+..] ----
    float inv = sg_mix / l_run;
    #pragma unroll
    for (int dlt = 0; dlt < 4; dlt++) {
        uint lo = (uint)f2bf(oacc[dlt][0] * inv) | ((uint)f2bf(oacc[dlt][1] * inv) << 16);
        uint hi = (uint)f2bf(oacc[dlt][2] * inv) | ((uint)f2bf(oacc[dlt][3] * inv) << 16);
        *(uint2*)&AG[(btd + q_glob) * 1024 + 512 + h * 64 + dlt * 16 + g * 4] = make_uint2(lo, hi);
    }
}

// ======================= launch =======================
extern "C" void kernel_launch(void* const* d_in, const int* in_sizes, int n_in,
                              void* d_out, int out_size, void* d_ws, size_t ws_size,
                              hipStream_t stream)
{
    const float* x    = (const float*)d_in[0];
    const float* cond = (const float*)d_in[1];
    const int*   tarr = (const int*)d_in[2];
    const float* lq_w = (const float*)d_in[3];
    const float* lq_b = (const float*)d_in[4];
    const float* lk_w = (const float*)d_in[5];
    const float* lk_b = (const float*)d_in[6];
    const float* lv_w = (const float*)d_in[7];
    const float* lv_b = (const float*)d_in[8];
    const float* lo_w = (const float*)d_in[9];
    const float* lo_b = (const float*)d_in[10];
    const float* gq_w = (const float*)d_in[11];
    const float* gq_b = (const float*)d_in[12];
    const float* gk_w = (const float*)d_in[13];
    const float* gk_b = (const float*)d_in[14];
    const float* gv_w = (const float*)d_in[15];
    const float* gv_b = (const float*)d_in[16];
    const float* go_w = (const float*)d_in[17];
    const float* go_b = (const float*)d_in[18];
    float* out = (float*)d_out;

    const size_t N = (size_t)BB * CC * TT;          // 4.19M elems
    char* w = (char*)d_ws;
    ushort* xtb = (ushort*)w; w += N * 2;           // x^T  [b][t][c]
    ushort* ctb = (ushort*)w; w += N * 2;           // cond^T
    ushort* lq  = (ushort*)w; w += N * 2;
    ushort* lk  = (ushort*)w; w += N * 2;
    ushort* lv  = (ushort*)w; w += N * 2;
    ushort* gqb = (ushort*)w; w += N * 2;
    ushort* gkb = (ushort*)w; w += N * 2;
    ushort* gvb = (ushort*)w; w += N * 2;           // [b][c][t]
    ushort* scr = (ushort*)w; w += N * 2;           // local-attn scrambled out
    ushort* AG  = (ushort*)w; w += (size_t)BB * TT * 1024 * 2;   // [b][t][sl*a | sg*g]
    ushort* wbf = (ushort*)w; w += (size_t)6 * 512 * 512 * 2;
    ushort* wc  = (ushort*)w; w += (size_t)512 * 1024 * 2;
    float* ctab = (float*)w;  w += (size_t)32 * 2048 * 4;
    float* stab = (float*)w;

    dim3 blk(256);

    rope_table_kernel<<<dim3(256), blk, 0, stream>>>(ctab, stab);
    wcvt_kernel<<<dim3(256, 8), blk, 0, stream>>>(lq_w, lk_w, lv_w, gq_w, gk_w, gv_w, lo_w, go_w, wbf, wc);
    transpose2_f32_kernel<<<dim3(32, 8, 8), blk, 0, stream>>>(x, cond, xtb, ctb);

    gemm6_kernel<<<dim3(64, 4, 6), blk, 0, stream>>>(wbf, lq_b, lk_b, lv_b, gq_b, gk_b, gv_b,
                                                     xtb, ctb, lq, lk, lv, gqb, gkb, gvb, ctab, stab);

    local_attn_kernel<<<dim3(BB * HH * TT / 256), blk, 0, stream>>>(lq, lk, lv, scr, tarr);
    transpose_bf16_kernel<<<dim3(32, 8, BB), blk, 0, stream>>>(scr, AG);

    flash_global_kernel<<<dim3(TT / 64, HH, BB), blk, 0, stream>>>(gqb, gkb, gvb, AG, tarr);

    gemm_comb_kernel<<<dim3(64, 4), blk, 0, stream>>>(wc, lo_b, go_b, AG, out, tarr);
}

// Round 7
// 198.602 us; speedup vs baseline: 19.0290x; 1.0394x over previous
//
#include <hip/hip_runtime.h>
#include <math.h>

#define BB 4
#define CC 512
#define TT 2048
#define HH 8
#define DD 64

static constexpr float SCALE = 0.125f;                 // D^-0.5
static constexpr float QK_SCALE_LOG2 = 0.125f * 1.4426950408889634f;  // fold log2(e): softmax in exp2 domain

typedef __attribute__((ext_vector_type(8))) short  short8;
typedef __attribute__((ext_vector_type(4))) float  f32x4;

static __device__ __forceinline__ ushort f2bf(float f) {
    uint u = __float_as_uint(f);
    uint r = (u + 0x7fffu + ((u >> 16) & 1u)) >> 16;
    return (ushort)r;
}
static __device__ __forceinline__ float bf2f(ushort u) {
    return __uint_as_float((uint)u << 16);
}

typedef unsigned int u32;
typedef u32 __attribute__((address_space(1))) gu32;
typedef u32 __attribute__((address_space(3))) lu32;
static __device__ __forceinline__ void gload_lds16(const void* g, void* l) {
    __builtin_amdgcn_global_load_lds((const gu32*)g, (lu32*)l, 16, 0, 0);
}

// ======================= RoPE cos/sin table, [i][t] layout =======================
__global__ void rope_table_kernel(float* __restrict__ ctab, float* __restrict__ stab)
{
    int idx = blockIdx.x * blockDim.x + threadIdx.x;   // 32*2048 threads
    int i = idx >> 11;
    int t = idx & 2047;
    float ex   = (2.0f * (float)i) / 64.0f;
    float invf = powf(10000.0f, -ex);
    float ang  = (float)t * invf;
    ctab[idx] = cosf(ang);
    stab[idx] = sinf(ang);
}

// ======================= weight fp32 -> bf16 =======================
// wi 0..5 -> wbf (qkv weights, 512x512 each); wi 6,7 -> wc combined [o][1024] halves
__global__ void wcvt_kernel(const float* w0, const float* w1, const float* w2, const float* w3,
                            const float* w4, const float* w5, const float* w6, const float* w7,
                            ushort* __restrict__ wbf, ushort* __restrict__ wc)
{
    const float* srcs[8] = {w0, w1, w2, w3, w4, w5, w6, w7};
    int wi = blockIdx.y;
    int idx = (blockIdx.x * 256 + threadIdx.x) * 4;
    float4 v = *(const float4*)&srcs[wi][idx];
    uint lo = (uint)f2bf(v.x) | ((uint)f2bf(v.y) << 16);
    uint hi = (uint)f2bf(v.z) | ((uint)f2bf(v.w) << 16);
    uint2 pk = make_uint2(lo, hi);
    if (wi < 6) {
        *(uint2*)&wbf[(size_t)wi * 262144 + idx] = pk;
    } else {
        int row = idx >> 9, col = idx & 511;
        *(uint2*)&wc[(size_t)row * 1024 + (wi - 6) * 512 + col] = pk;
    }
}

// ======================= transpose [b][c][t] -> bf16 [b][t][c]  (x & cond fused) =======================
__global__ __launch_bounds__(256)
void transpose2_f32_kernel(const float* __restrict__ x, const float* __restrict__ cond,
                           ushort* __restrict__ xtb, ushort* __restrict__ ctb)
{
    __shared__ ushort L[64][66];
    const int z = blockIdx.z;                 // 0..7
    const float* in = (z < 4) ? x : cond;
    ushort* outp    = (z < 4) ? xtb : ctb;
    const int b = z & 3;
    const int t0 = blockIdx.x * 64, c0 = blockIdx.y * 64;
    const float* inb = in + (size_t)b * CC * TT;
    ushort* outb = outp + (size_t)b * TT * CC;
    const int lc = threadIdx.x >> 6;
    const int lt = threadIdx.x & 63;
    #pragma unroll
    for (int i = 0; i < 16; i++) {
        int c = i * 4 + lc;
        L[c][lt] = f2bf(inb[(size_t)(c0 + c) * TT + t0 + lt]);
    }
    __syncthreads();
    #pragma unroll
    for (int i = 0; i < 16; i++) {
        int t = i * 4 + lc;
        outb[(size_t)(t0 + t) * CC + c0 + lt] = L[lt][t];
    }
}

// ---- scrambled local-attn output [b][c][t] -> AG[b][t][0..512) (row stride 1024) ----
__global__ __launch_bounds__(256)
void transpose_bf16_kernel(const ushort* __restrict__ in, ushort* __restrict__ AG)
{
    __shared__ ushort L[64][66];
    const int t0 = blockIdx.x * 64, c0 = blockIdx.y * 64, b = blockIdx.z;
    const ushort* inb = in + (size_t)b * CC * TT;
    ushort* outb = AG + (size_t)b * TT * 1024;
    const int lc = threadIdx.x >> 6;
    const int lt = threadIdx.x & 63;
    #pragma unroll
    for (int i = 0; i < 16; i++) {
        int c = i * 4 + lc;
        L[c][lt] = inb[(size_t)(c0 + c) * TT + t0 + lt];
    }
    __syncthreads();
    #pragma unroll
    for (int i = 0; i < 16; i++) {
        int t = i * 4 + lc;
        outb[(size_t)(t0 + t) * 1024 + c0 + lt] = L[lt][t];
    }
}

// ======================= MFMA GEMM core (shared macro-body; K-dim + N-tile params) =======================
// C[m=512][n-tile NB per block] = Wp[m][KD] . XTp[n][KD]; acc left in acc[4][NB/32].
#define GEMM_BODY(Wp, XTp, KD, NB)                                                  \
    __shared__ __align__(16) ushort As[2][128][32];                                 \
    __shared__ __align__(16) ushort Bs[2][NB][32];                                  \
    const int tid  = threadIdx.x;                                                   \
    const int wid  = tid >> 6;                                                      \
    const int lane = tid & 63;                                                      \
    const int x  = lane & 15;                                                       \
    const int gq = lane >> 4;                                                       \
    const int wm = wid >> 1, wn = wid & 1;                                          \
    const int m0 = blockIdx.y * 128;                                                \
    const int n0 = blockIdx.x * NB;                                                 \
    const int srow = lane >> 2;                                                     \
    const int sblk = lane & 3;                                                      \
    f32x4 acc[4][NB / 32];                                                          \
    _Pragma("unroll")                                                               \
    for (int i = 0; i < 4; i++)                                                     \
        _Pragma("unroll")                                                           \
        for (int j = 0; j < NB / 32; j++) acc[i][j] = (f32x4){0.f, 0.f, 0.f, 0.f};  \
    auto stage = [&](int bf, int k0) {                                              \
        _Pragma("unroll")                                                           \
        for (int c = 0; c < 2; c++) {                                               \
            int row = c * 64 + wid * 16 + srow;                                     \
            int dbk = sblk ^ ((row >> 1) & 3);                                      \
            gload_lds16(&Wp[(size_t)(m0 + row) * KD + k0 + dbk * 8],                \
                        &As[bf][c * 64 + wid * 16][0]);                             \
            if (c * 64 < NB)                                                        \
                gload_lds16(&XTp[(size_t)(n0 + row) * KD + k0 + dbk * 8],           \
                            &Bs[bf][c * 64 + wid * 16][0]);                         \
        }                                                                           \
    };                                                                              \
    stage(0, 0);                                                                    \
    __syncthreads();                                                                \
    for (int ks = 0; ks < (KD) / 32; ks++) {                                        \
        int cur = ks & 1;                                                           \
        if (ks < (KD) / 32 - 1) stage(cur ^ 1, (ks + 1) * 32);                      \
        short8 aF[4], bF[NB / 32];                                                  \
        _Pragma("unroll")                                                           \
        for (int mi = 0; mi < 4; mi++) {                                            \
            int row = wm * 64 + mi * 16 + x;                                        \
            aF[mi] = *(const short8*)&As[cur][row][(gq ^ ((row >> 1) & 3)) * 8];    \
        }                                                                           \
        _Pragma("unroll")                                                           \
        for (int nj = 0; nj < NB / 32; nj++) {                                      \
            int row = wn * (NB / 2) + nj * 16 + x;                                  \
            bF[nj] = *(const short8*)&Bs[cur][row][(gq ^ ((row >> 1) & 3)) * 8];    \
        }                                                                           \
        _Pragma("unroll")                                                           \
        for (int mi = 0; mi < 4; mi++)                                              \
            _Pragma("unroll")                                                       \
            for (int nj = 0; nj < NB / 32; nj++)                                    \
                acc[mi][nj] = __builtin_amdgcn_mfma_f32_16x16x32_bf16(aF[mi], bF[nj], acc[mi][nj], 0, 0, 0); \
        __syncthreads();                                                            \
    }

// ---- all 6 qkv projections in one dispatch ----
// z0:lq z1:lk z2:lv (bf16 C^T) | z3:gq (C^T, rope, qscale) z4:gk (C^T, rope) z5:gv (natural)
__global__ __launch_bounds__(256)
void gemm6_kernel(const ushort* __restrict__ wbase,
                  const float* __restrict__ b0, const float* __restrict__ b1, const float* __restrict__ b2,
                  const float* __restrict__ b3, const float* __restrict__ b4, const float* __restrict__ b5,
                  const ushort* __restrict__ xtb, const ushort* __restrict__ ctb,
                  ushort* __restrict__ y0, ushort* __restrict__ y1, ushort* __restrict__ y2,
                  ushort* __restrict__ y3, ushort* __restrict__ y4, ushort* __restrict__ y5,
                  const float* __restrict__ ctab, const float* __restrict__ stab)
{
    const int z = blockIdx.z;
    const ushort* Wp  = wbase + (size_t)z * 262144;
    const float* bias = (z == 0) ? b0 : (z == 1) ? b1 : (z == 2) ? b2 : (z == 3) ? b3 : (z == 4) ? b4 : b5;
    const ushort* XTp = (z == 0 || z == 3) ? xtb : ctb;
    ushort* Y = (z == 0) ? y0 : (z == 1) ? y1 : (z == 2) ? y2 : (z == 3) ? y3 : (z == 4) ? y4 : y5;
    const bool do_rope = (z == 3 || z == 4);
    const float qscale = (z == 3) ? QK_SCALE_LOG2 : 1.0f;

    GEMM_BODY(Wp, XTp, 512, 128)

    const int bidx = (n0 + wn * 64) >> 11;
    #pragma unroll
    for (int mi = 0; mi < 4; mi++) {
        const int mb = m0 + wm * 64 + mi * 16 + 4 * gq;
        float bv[4];
        #pragma unroll
        for (int r = 0; r < 4; r++) bv[r] = bias[mb + r];
        #pragma unroll
        for (int nj = 0; nj < 4; nj++) {
            const int n  = n0 + wn * 64 + nj * 16 + x;
            const int tt = n & 2047;
            f32x4 v = acc[mi][nj];
            v[0] += bv[0]; v[1] += bv[1]; v[2] += bv[2]; v[3] += bv[3];
            if (do_rope) {
                const int i0 = (mb & 63) >> 1;
                float c0 = ctab[(size_t)i0 * 2048 + tt],       s0 = stab[(size_t)i0 * 2048 + tt];
                float c1 = ctab[(size_t)(i0 + 1) * 2048 + tt], s1 = stab[(size_t)(i0 + 1) * 2048 + tt];
                float e0 = (v[0] * c0 - v[1] * s0) * qscale;
                float e1 = (v[0] * s0 + v[1] * c0) * qscale;
                float e2 = (v[2] * c1 - v[3] * s1) * qscale;
                float e3 = (v[2] * s1 + v[3] * c1) * qscale;
                v[0] = e0; v[1] = e1; v[2] = e2; v[3] = e3;
            }
            if (z != 5) {      // bf16 C^T [b][t][c]
                uint lo = (uint)f2bf(v[0]) | ((uint)f2bf(v[1]) << 16);
                uint hi = (uint)f2bf(v[2]) | ((uint)f2bf(v[3]) << 16);
                *(uint2*)&Y[(size_t)n * 512 + mb] = make_uint2(lo, hi);
            } else {           // bf16 natural [b][c][t]  (global v)
                #pragma unroll
                for (int r = 0; r < 4; r++)
                    Y[((size_t)bidx * 512 + mb + r) * 2048 + tt] = f2bf(v[r]);
            }
        }
    }
}

// ---- combined output projection (NB=64, 512 blocks): d_out = Wc[512][1024].AG[n][1024] + mixed bias ----
__global__ __launch_bounds__(256)
void gemm_comb_kernel(const ushort* __restrict__ Wp,
                      const float* __restrict__ bl, const float* __restrict__ bg,
                      const ushort* __restrict__ XTp, float* __restrict__ Y,
                      const int* __restrict__ tarr)
{
    GEMM_BODY(Wp, XTp, 1024, 64)

    const int bidx = (n0 + wn * 32) >> 11;
    float tn = (float)tarr[bidx] / 999.0f;
    float sl = sqrtf(tn), sg = sqrtf(1.0f - tn);

    #pragma unroll
    for (int mi = 0; mi < 4; mi++) {
        const int mb = m0 + wm * 64 + mi * 16 + 4 * gq;
        float bv[4];
        #pragma unroll
        for (int r = 0; r < 4; r++) bv[r] = sl * bl[mb + r] + sg * bg[mb + r];
        #pragma unroll
        for (int nj = 0; nj < 2; nj++) {
            const int tt = (n0 + wn * 32 + nj * 16 + x) & 2047;
            f32x4 v = acc[mi][nj];
            #pragma unroll
            for (int r = 0; r < 4; r++)
                Y[((size_t)bidx * 512 + mb + r) * 2048 + tt] = v[r] + bv[r];
        }
    }
}

// ======================= local windowed attention (bf16 [t][c] in, sl-scaled out) =======================
__global__ __launch_bounds__(256)
void local_attn_kernel(const ushort* __restrict__ qt, const ushort* __restrict__ kt,
                       const ushort* __restrict__ vt, ushort* __restrict__ outb,
                       const int* __restrict__ tarr)
{
    int gidx = blockIdx.x * 256 + threadIdx.x;
    int t  = gidx & (TT - 1);
    int bh = gidx >> 11;
    int h  = bh & (HH - 1);
    int b  = bh >> 3;
    const size_t rb = (size_t)b * TT;
    const int co = h * DD;
    const float wl = sqrtf((float)tarr[b] / 999.0f);

    float qf[64];
    {
        const ushort* qp = qt + (rb + t) * 512 + co;
        #pragma unroll
        for (int i = 0; i < 8; i++) {
            short8 v = *(const short8*)&qp[i * 8];
            #pragma unroll
            for (int j = 0; j < 8; j++) qf[i * 8 + j] = bf2f((ushort)v[j]);
        }
    }

    int koff[16]; float msk[16];
    #pragma unroll
    for (int w = 0; w < 16; w++) {
        int kidx = t + w - 8;
        msk[w]  = (kidx >= 0 && kidx < TT) ? 1.0f : 0.0f;
        koff[w] = min(max(kidx, 0), TT - 1);
    }

    float dots[16];
    #pragma unroll
    for (int w = 0; w < 16; w++) {
        const ushort* kp = kt + (rb + koff[w]) * 512 + co;
        float d0 = 0.f, d1 = 0.f;
        #pragma unroll
        for (int i = 0; i < 8; i++) {
            short8 v = *(const short8*)&kp[i * 8];
            #pragma unroll
            for (int j = 0; j < 8; j += 2) {
                d0 = fmaf(qf[i * 8 + j],     bf2f((ushort)v[j]),     d0);
                d1 = fmaf(qf[i * 8 + j + 1], bf2f((ushort)v[j + 1]), d1);
            }
        }
        dots[w] = d0 + d1;
    }

    float m = -1e30f;
    #pragma unroll
    for (int w = 0; w < 16; w++) { dots[w] = dots[w] * SCALE * msk[w]; m = fmaxf(m, dots[w]); }
    float p[16], s = 0.f;
    #pragma unroll
    for (int w = 0; w < 16; w++) { p[w] = __expf(dots[w] - m); s += p[w]; }
    float inv = wl / s;                       // fold the mix weight into the normalize
    #pragma unroll
    for (int w = 0; w < 16; w++) p[w] *= msk[w] * inv;

    float oa[64];
    #pragma unroll
    for (int d = 0; d < 64; d++) oa[d] = 0.f;
    #pragma unroll
    for (int w = 0; w < 16; w++) {
        const ushort* vp = vt + (rb + koff[w]) * 512 + co;
        #pragma unroll
        for (int i = 0; i < 8; i++) {
            short8 v = *(const short8*)&vp[i * 8];
            #pragma unroll
            for (int j = 0; j < 8; j++)
                oa[i * 8 + j] = fmaf(p[w], bf2f((ushort)v[j]), oa[i * 8 + j]);
        }
    }

    // scrambled store (reference's (B,H,T,D)->(B,C,T) reshape), bf16 [c'][t']
    ushort* op = outb + ((size_t)b * CC + co + (t >> 5)) * TT + (size_t)(t & 31) * DD;
    #pragma unroll
    for (int i = 0; i < 16; i++) {
        uint lo = (uint)f2bf(oa[i * 4 + 0]) | ((uint)f2bf(oa[i * 4 + 1]) << 16);
        uint hi = (uint)f2bf(oa[i * 4 + 2]) | ((uint)f2bf(oa[i * 4 + 3]) << 16);
        *(uint2*)&op[i * 4] = make_uint2(lo, hi);
    }
}

// ======================= global flash attention (bf16 MFMA, swapped-S, exp2, gload_lds dbuf) =======================
// q: [b][t][c] pre-scaled by SCALE*log2e + RoPE'd; k: [b][t][c] RoPE'd; v: [b][c][t].
// out: AG[b][t][512..1024) scaled by sg (row stride 1024).
// LDS layouts (same swizzle as verified r5/r6, now written by global_load_lds with
// pre-swizzled per-lane SOURCE addresses — linear LDS dest, m173 pattern):
//   Ks byte(tk,d) = 128*tk + 16*((d>>3)^(tk&7)) + 2*(d&7)
//   Vs byte(d,t)  = 128*d  + 16*((t>>3)^(d&7))  + 2*(t&7)
//   Ps byte(row=wid*16+q, k) = 128*row + 16*((k>>3)^(q&7)) + 2*(k&7)   [wave-private rows]
// Double-buffered K/V, ONE barrier per tile: bar -> issue loads(kt+1 -> buf^1) -> compute(buf).
__global__ __launch_bounds__(256)
void flash_global_kernel(const ushort* __restrict__ qtd, const ushort* __restrict__ ktd,
                         const ushort* __restrict__ vb, ushort* __restrict__ AG,
                         const int* __restrict__ tarr)
{
    __shared__ __align__(16) ushort Ks[2][4096];
    __shared__ __align__(16) ushort Vs[2][4096];
    __shared__ __align__(16) ushort Ps[4096];

    const int tid  = threadIdx.x;
    const int wid  = tid >> 6;
    const int lane = tid & 63;
    const int x    = lane & 15;
    const int g    = lane >> 4;

    const int q0 = blockIdx.x * 64;
    const int h  = blockIdx.y;
    const int b  = blockIdx.z;
    const size_t bh_ct = ((size_t)b * CC + h * DD) * TT;   // v [b][c][t]
    const size_t btd   = (size_t)b * TT;                   // [b][t][c] row base
    const int q_glob = q0 + wid * 16 + x;
    const int prow = wid * 16 + x;        // wave-private Ps row
    const float sg_mix = sqrtf(1.0f - (float)tarr[b] / 999.0f);

    // ---- Q fragments (B-operand): lane supplies Q[q=x][d = kap*32 + g*8 + j] ----
    short8 aQ[2];
    {
        const ushort* qrow = qtd + (btd + q_glob) * 512 + h * 64;
        aQ[0] = *(const short8*)&qrow[g * 8];
        aQ[1] = *(const short8*)&qrow[32 + g * 8];
    }

    f32x4 oacc[4];
    #pragma unroll
    for (int d = 0; d < 4; d++) oacc[d] = (f32x4){0.f, 0.f, 0.f, 0.f};
    float m_run = -INFINITY, l_run = 0.0f;

    // ---- gload_lds staging: linear dest chunk L = tid covers LDS bytes [16L,16L+16) ----
    // K: L -> (tk = L>>3, pos = L&7); source d-block = pos ^ (tk&7)  [inverse swizzle]
    // V: L -> (d  = L>>3, tpos = L&7); source t-block = tpos ^ (d&7)  [same expression]
    const int rowq = tid >> 3;
    const int pos  = tid & 7;
    const int blk  = pos ^ (rowq & 7);
    const ushort* kA = ktd + (btd + rowq) * 512 + h * 64 + blk * 8;
    const ushort* kB = kA + 32 * 512;
    const ushort* vA = vb + bh_ct + (size_t)rowq * TT + blk * 8;
    const ushort* vB = vA + (size_t)32 * TT;

    auto issue = [&](int buf) {
        gload_lds16(kA, &Ks[buf][wid * 512]);
        gload_lds16(kB, &Ks[buf][2048 + wid * 512]);
        gload_lds16(vA, &Vs[buf][wid * 512]);
        gload_lds16(vB, &Vs[buf][2048 + wid * 512]);
        kA += 64 * 512; kB += 64 * 512; vA += 64; vB += 64;
    };
    issue(0);

    int cur = 0;
    for (int kt = 0; kt < 32; kt++) {
        __syncthreads();                // drains vmcnt (buf 'cur' ready) + all waves done reading buf cur^1
        if (kt < 31) issue(cur ^ 1);    // async loads overlap the whole compute phase

        const ushort* KsC = &Ks[cur][0];
        const ushort* VsC = &Vs[cur][0];

        // ---- S^T = K Q^T : ST[tau][r] = S[k=16tau+4g+r][q=x]  (log2 units) ----
        f32x4 ST[4];
        #pragma unroll
        for (int tau = 0; tau < 4; tau++) ST[tau] = (f32x4){0.f, 0.f, 0.f, 0.f};
        __builtin_amdgcn_s_setprio(1);
        #pragma unroll
        for (int kap = 0; kap < 2; kap++)
            #pragma unroll
            for (int tau = 0; tau < 4; tau++) {
                short8 aK = *(const short8*)&KsC[(tau * 16 + x) * 64 + (((4 * kap + g) ^ (x & 7)) << 3)];
                ST[tau] = __builtin_amdgcn_mfma_f32_16x16x32_bf16(aK, aQ[kap], ST[tau], 0, 0, 0);
            }
        __builtin_amdgcn_s_setprio(0);

        // ---- online softmax (q = x per-lane; reduce across g only); max3-friendly tree ----
        float m1 = fmaxf(fmaxf(ST[0][0], ST[0][1]), ST[0][2]);
        float m2 = fmaxf(fmaxf(ST[0][3], ST[1][0]), ST[1][1]);
        float m3 = fmaxf(fmaxf(ST[1][2], ST[1][3]), ST[2][0]);
        float m4 = fmaxf(fmaxf(ST[2][1], ST[2][2]), ST[2][3]);
        float m5 = fmaxf(fmaxf(ST[3][0], ST[3][1]), ST[3][2]);
        float mr = fmaxf(fmaxf(fmaxf(m1, m2), m3), fmaxf(fmaxf(m4, m5), ST[3][3]));
        mr = fmaxf(mr, __shfl_xor(mr, 16));
        mr = fmaxf(mr, __shfl_xor(mr, 32));

        // T13 defer-rescale: only rescale when some query's max grew by > 8 (log2 units)
        if (__any(mr > m_run + 8.0f)) {
            float mnew = fmaxf(m_run, mr);
            float corr = __builtin_amdgcn_exp2f(m_run - mnew);
            m_run = mnew;
            l_run *= corr;
            #pragma unroll
            for (int d = 0; d < 4; d++) {
                oacc[d][0] *= corr; oacc[d][1] *= corr;
                oacc[d][2] *= corr; oacc[d][3] *= corr;
            }
        }

        float sm = 0.0f;
        #pragma unroll
        for (int tau = 0; tau < 4; tau++) {
            ST[tau][0] = __builtin_amdgcn_exp2f(ST[tau][0] - m_run);
            ST[tau][1] = __builtin_amdgcn_exp2f(ST[tau][1] - m_run);
            ST[tau][2] = __builtin_amdgcn_exp2f(ST[tau][2] - m_run);
            ST[tau][3] = __builtin_amdgcn_exp2f(ST[tau][3] - m_run);
            sm += (ST[tau][0] + ST[tau][1]) + (ST[tau][2] + ST[tau][3]);
        }
        sm += __shfl_xor(sm, 16);
        sm += __shfl_xor(sm, 32);
        l_run += sm;

        // ---- P -> Ps via cvt_pk (4x uint2 writes into wave-private row) ----
        #pragma unroll
        for (int tau = 0; tau < 4; tau++) {
            uint lo, hi;
            asm("v_cvt_pk_bf16_f32 %0, %1, %2" : "=v"(lo) : "v"(ST[tau][0]), "v"(ST[tau][1]));
            asm("v_cvt_pk_bf16_f32 %0, %1, %2" : "=v"(hi) : "v"(ST[tau][2]), "v"(ST[tau][3]));
            int kblk = 2 * tau + (g >> 1);
            *(uint2*)&Ps[prow * 64 + ((kblk ^ (x & 7)) << 3) + (g & 1) * 4] = make_uint2(lo, hi);
        }

        // ---- PV: out^T += V^T P^T  (bP = b128 reads of own-q wave-private row) ----
        short8 bP[2];
        bP[0] = *(const short8*)&Ps[prow * 64 + (((g    ) ^ (x & 7)) << 3)];
        bP[1] = *(const short8*)&Ps[prow * 64 + (((4 + g) ^ (x & 7)) << 3)];
        __builtin_amdgcn_s_setprio(1);
        #pragma unroll
        for (int dlt = 0; dlt < 4; dlt++)
            #pragma unroll
            for (int kap = 0; kap < 2; kap++) {
                short8 aV = *(const short8*)&VsC[(dlt * 16 + x) * 64 + (((4 * kap + g) ^ (x & 7)) << 3)];
                oacc[dlt] = __builtin_amdgcn_mfma_f32_16x16x32_bf16(aV, bP[kap], oacc[dlt], 0, 0, 0);
            }
        __builtin_amdgcn_s_setprio(0);
        cur ^= 1;
    }

    // ---- final normalize (per-lane, sg mix folded) + store bf16 AG[b][t][512+..] ----
    float inv = sg_mix / l_run;
    #pragma unroll
    for (int dlt = 0; dlt < 4; dlt++) {
        uint lo = (uint)f2bf(oacc[dlt][0] * inv) | ((uint)f2bf(oacc[dlt][1] * inv) << 16);
        uint hi = (uint)f2bf(oacc[dlt][2] * inv) | ((uint)f2bf(oacc[dlt][3] * inv) << 16);
        *(uint2*)&AG[(btd + q_glob) * 1024 + 512 + h * 64 + dlt * 16 + g * 4] = make_uint2(lo, hi);
    }
}

// ======================= launch =======================
extern "C" void kernel_launch(void* const* d_in, const int* in_sizes, int n_in,
                              void* d_out, int out_size, void* d_ws, size_t ws_size,
                              hipStream_t stream)
{
    const float* x    = (const float*)d_in[0];
    const float* cond = (const float*)d_in[1];
    const int*   tarr = (const int*)d_in[2];
    const float* lq_w = (const float*)d_in[3];
    const float* lq_b = (const float*)d_in[4];
    const float* lk_w = (const float*)d_in[5];
    const float* lk_b = (const float*)d_in[6];
    const float* lv_w = (const float*)d_in[7];
    const float* lv_b = (const float*)d_in[8];
    const float* lo_w = (const float*)d_in[9];
    const float* lo_b = (const float*)d_in[10];
    const float* gq_w = (const float*)d_in[11];
    const float* gq_b = (const float*)d_in[12];
    const float* gk_w = (const float*)d_in[13];
    const float* gk_b = (const float*)d_in[14];
    const float* gv_w = (const float*)d_in[15];
    const float* gv_b = (const float*)d_in[16];
    const float* go_w = (const float*)d_in[17];
    const float* go_b = (const float*)d_in[18];
    float* out = (float*)d_out;

    const size_t N = (size_t)BB * CC * TT;          // 4.19M elems
    char* w = (char*)d_ws;
    ushort* xtb = (ushort*)w; w += N * 2;           // x^T  [b][t][c]
    ushort* ctb = (ushort*)w; w += N * 2;           // cond^T
    ushort* lq  = (ushort*)w; w += N * 2;
    ushort* lk  = (ushort*)w; w += N * 2;
    ushort* lv  = (ushort*)w; w += N * 2;
    ushort* gqb = (ushort*)w; w += N * 2;
    ushort* gkb = (ushort*)w; w += N * 2;
    ushort* gvb = (ushort*)w; w += N * 2;           // [b][c][t]
    ushort* scr = (ushort*)w; w += N * 2;           // local-attn scrambled out
    ushort* AG  = (ushort*)w; w += (size_t)BB * TT * 1024 * 2;   // [b][t][sl*a | sg*g]
    ushort* wbf = (ushort*)w; w += (size_t)6 * 512 * 512 * 2;
    ushort* wc  = (ushort*)w; w += (size_t)512 * 1024 * 2;
    float* ctab = (float*)w;  w += (size_t)32 * 2048 * 4;
    float* stab = (float*)w;

    dim3 blk(256);

    rope_table_kernel<<<dim3(256), blk, 0, stream>>>(ctab, stab);
    wcvt_kernel<<<dim3(256, 8), blk, 0, stream>>>(lq_w, lk_w, lv_w, gq_w, gk_w, gv_w, lo_w, go_w, wbf, wc);
    transpose2_f32_kernel<<<dim3(32, 8, 8), blk, 0, stream>>>(x, cond, xtb, ctb);

    gemm6_kernel<<<dim3(64, 4, 6), blk, 0, stream>>>(wbf, lq_b, lk_b, lv_b, gq_b, gk_b, gv_b,
                                                     xtb, ctb, lq, lk, lv, gqb, gkb, gvb, ctab, stab);

    local_attn_kernel<<<dim3(BB * HH * TT / 256), blk, 0, stream>>>(lq, lk, lv, scr, tarr);
    transpose_bf16_kernel<<<dim3(32, 8, BB), blk, 0, stream>>>(scr, AG);

    flash_global_kernel<<<dim3(TT / 64, HH, BB), blk, 0, stream>>>(gqb, gkb, gvb, AG, tarr);

    gemm_comb_kernel<<<dim3(128, 4), blk, 0, stream>>>(wc, lo_b, go_b, AG, out, tarr);
}